// Round 19
// baseline (260.134 us; speedup 1.0000x reference)
//
#include <hip/hip_runtime.h>
#include <math.h>

#define TPB 256

typedef unsigned short us16;
typedef __bf16 bf16x8 __attribute__((ext_vector_type(8)));
typedef float f32x4 __attribute__((ext_vector_type(4)));

static const int B_ALL = 4;
static const int CH   = 64;
static const int HIN  = 256, WIN = 256;
static const int HH   = 255;
static const int WF   = 129;          // valid n per channel
static const int HWF  = HH * WF;      // 32895 valid GN count per channel
static const int SP   = WF * 256;     // 33024 packed spatial per channel
static const int KH   = 160;          // padded K for inverse W-DFT
static const int UZ   = 64 * WF;      // 8256 packed (c,n) rows per batch (inv side)
static const int NBX  = 258;          // fwd2 blocks per batch (128*129/64)
#define GN_EPS 1e-5f

__device__ __forceinline__ us16 f2bf(float f) {
  union { float f; unsigned u; } v; v.f = f;
  unsigned r = v.u + 0x7FFFu + ((v.u >> 16) & 1u);
  return (us16)(r >> 16);
}
__device__ __forceinline__ float bf2f(us16 v) {
  union { unsigned u; float f; } t; t.u = ((unsigned)v) << 16; return t.f;
}
__device__ __forceinline__ void gload16(const void* g, void* l) {
  __builtin_amdgcn_global_load_lds(
      (const __attribute__((address_space(1))) unsigned int*)g,
      (__attribute__((address_space(3))) unsigned int*)l, 16, 0, 0);
}
#define MFMA __builtin_amdgcn_mfma_f32_16x16x32_bf16
#define WAITVM(N) asm volatile("s_waitcnt vmcnt(" #N ")" ::: "memory")
#define BAR_ACQ() do { \
    __builtin_amdgcn_s_barrier(); \
    asm volatile("" ::: "memory"); \
    __builtin_amdgcn_sched_barrier(0); } while (0)
#define BAR_REL() do { \
    asm volatile("" ::: "memory"); \
    __builtin_amdgcn_s_barrier(); } while (0)

// ---------------- fallback ----------------
__global__ __launch_bounds__(TPB) void k_zero(float* __restrict__ out, int n) {
  int i = blockIdx.x * TPB + threadIdx.x;
  if (i < n) out[i] = 0.f;
}

// ---- cast x f32->bf16 (one wave per row) + analytic Nyquist bin n=128 ----
__global__ __launch_bounds__(TPB) void k_xcast2(const float* __restrict__ x,
                                                us16* __restrict__ xb,
                                                us16* __restrict__ Frt,
                                                us16* __restrict__ Fit) {
  const int row = blockIdx.x * 4 + (threadIdx.x >> 6);
  const int lane = threadIdx.x & 63;
  float4 v = ((const float4*)(x + (size_t)row * 256))[lane];
  ushort4 o;
  o.x = f2bf(v.x); o.y = f2bf(v.y); o.z = f2bf(v.z); o.w = f2bf(v.w);
  ((ushort4*)(xb + (size_t)row * 256))[lane] = o;
  float alt = v.x - v.y + v.z - v.w;
  for (int off = 32; off; off >>= 1) alt += __shfl_down(alt, off);
  if (lane == 0) {
    int bc = row >> 8, h = row & 255;
    size_t idx = ((size_t)bc * WF + 128) * 256 + h;
    Frt[idx] = f2bf(alt);
    Fit[idx] = 0;
  }
}

// ---------------- bf16 tables + f32 rotation LUT ----------------
__global__ __launch_bounds__(TPB) void k_tables(
    us16* __restrict__ CbA, us16* __restrict__ SbA,
    us16* __restrict__ Tcb, us16* __restrict__ Tsb,
    us16* __restrict__ Tci, us16* __restrict__ Tsi,
    us16* __restrict__ Wpb, us16* __restrict__ Wqb,
    float* __restrict__ rot,
    const float* __restrict__ conv_w) {
  int i = blockIdx.x * TPB + threadIdx.x;
  const double PI2 = 6.283185307179586476925286766559;
  if (i < 2 * 65536) {                      // H-DFT [fu][r][k], k-shift absorbed
    int fu = i >> 16, r = (i >> 8) & 255, k = i & 255;
    float cv = 0.f, sv = 0.f;
    int kk = k - fu;
    if (r < 255 && kk >= 0 && kk < 255) {
      double ang = PI2 * (double)((r * kk) % 255) / 255.0;
      cv = (float)cos(ang); sv = (float)sin(ang);
    }
    CbA[i] = f2bf(cv); SbA[i] = f2bf(sv);
  }
  if (i < 128 * 256) {                      // W-DFT fwd transposed [n<128][w]
    int n = i >> 8, w = i & 255;
    double ang = PI2 * (double)((n * w) & 255) / 256.0;
    Tcb[i] = f2bf((float)cos(ang));
    Tsb[i] = f2bf((float)sin(ang));
  }
  if (i < 256 * KH) {                       // W-DFT inv [w][k], Hermitian coef
    int w = i / KH, k = i - w * KH;
    float cv = 0.f, sv = 0.f;
    if (k < WF) {
      double coef = (k == 0 || k == 128) ? 1.0 : 2.0;
      double ang = PI2 * (double)((k * w) & 255) / 256.0;
      cv = (float)(coef * cos(ang) / 256.0);
      sv = (float)(coef * sin(ang) / 256.0);
    }
    Tci[i] = f2bf(cv); Tsi[i] = f2bf(sv);
  }
  if (i < 128 * 128) {                      // mix weights
    int o = i >> 7, c = i & 127;
    Wpb[i] = f2bf(conv_w[i]);
    float q = (c < 64) ? -conv_w[o * 128 + 64 + c] : conv_w[o * 128 + c - 64];
    Wqb[i] = f2bf(q);
  }
  if (i < 128) {                            // fu1 rotation per output row r
    double ang = PI2 * (double)i / 255.0;
    rot[2 * i] = (float)cos(ang);
    rot[2 * i + 1] = (float)sin(ang);
  }
}

// ------- K1: forward W-DFT, BOTH n-halves per block (B staged once) -------
__global__ __launch_bounds__(TPB) void k_dftw_fwd_mfma(
    const us16* __restrict__ xb, const us16* __restrict__ Tcb,
    const us16* __restrict__ Tsb, us16* __restrict__ Frt, us16* __restrict__ Fit) {
  __shared__ __align__(16) us16 Ac[2][2][64][32];   // [pp][half]
  __shared__ __align__(16) us16 As[2][2][64][32];
  __shared__ __align__(16) us16 Bx[2][64][32];
  const int tid = threadIdx.x, w = tid >> 6, lane = tid & 63;
  const int hb = blockIdx.x;
  const int rsel = lane >> 2;
  const int csw = (lane & 3) ^ ((lane >> 3) & 3);
  const us16* gAc = Tcb + (size_t)(16 * w + rsel) * 256 + csw * 8;
  const us16* gAs = Tsb + (size_t)(16 * w + rsel) * 256 + csw * 8;
  const us16* gB  = xb + ((size_t)hb * 64 + 16 * w + rsel) * 256 + csw * 8;
  f32x4 accr[2][4] = {}, acci[2][4] = {};
  const int fr = lane & 15;
  const int kb = 8 * ((lane >> 4) ^ ((lane >> 1) & 3));
#define STAGE_K1(pp, k0) do { \
    gload16(gAc + (k0), &Ac[pp][0][16 * w][0]); \
    gload16(gAc + 64 * 256 + (k0), &Ac[pp][1][16 * w][0]); \
    gload16(gAs + (k0), &As[pp][0][16 * w][0]); \
    gload16(gAs + 64 * 256 + (k0), &As[pp][1][16 * w][0]); \
    gload16(gB + (k0), &Bx[pp][16 * w][0]); } while (0)
  STAGE_K1(0, 0);
  int pp = 0;
  for (int k0 = 0; k0 < 256; k0 += 32) {
    if (k0 + 32 < 256) { STAGE_K1(pp ^ 1, k0 + 32); WAITVM(5); }
    else WAITVM(0);
    BAR_ACQ();
    bf16x8 aC[2], aSn[2];
#pragma unroll
    for (int g = 0; g < 2; ++g) {
      aC[g] = *(const bf16x8*)&Ac[pp][g][16 * w + fr][kb];
      bf16x8 aS = *(const bf16x8*)&As[pp][g][16 * w + fr][kb];
      uint4 su = *(const uint4*)&aS;
      su.x ^= 0x80008000u; su.y ^= 0x80008000u; su.z ^= 0x80008000u; su.w ^= 0x80008000u;
      aSn[g] = *(const bf16x8*)&su;
    }
#pragma unroll
    for (int t = 0; t < 4; ++t) {
      bf16x8 b = *(const bf16x8*)&Bx[pp][16 * t + fr][kb];
#pragma unroll
      for (int g = 0; g < 2; ++g) {
        accr[g][t] = MFMA(aC[g], b, accr[g][t], 0, 0, 0);
        acci[g][t] = MFMA(aSn[g], b, acci[g][t], 0, 0, 0);
      }
    }
    BAR_REL();
    pp ^= 1;
  }
  const int bc = hb >> 2, hl = (hb & 3) * 64;
#pragma unroll
  for (int g = 0; g < 2; ++g) {
#pragma unroll
    for (int t = 0; t < 4; ++t) {
      int h = hl + 16 * t + fr;
#pragma unroll
      for (int j = 0; j < 4; ++j) {
        int n = g * 64 + 16 * w + 4 * (lane >> 4) + j;
        size_t idx = ((size_t)bc * WF + n) * 256 + h;
        Frt[idx] = f2bf(accr[g][t][j]);
        Fit[idx] = f2bf(acci[g][t][j]);
      }
    }
  }
}

// ------- K2: channel-mix, BOTH o-tiles per block (B staged once) -------
__global__ __launch_bounds__(TPB) void k_mix(
    const us16* __restrict__ Frt, const us16* __restrict__ Fit,
    const us16* __restrict__ Wpb, const us16* __restrict__ Wqb,
    us16* __restrict__ P, us16* __restrict__ Q) {
  __shared__ __align__(16) us16 Ap[2][64][32];
  __shared__ __align__(16) us16 Aq[2][64][32];
  __shared__ __align__(8)  us16 Bs[64][36];
  const int tid = threadIdx.x, w = tid >> 6, lane = tid & 63;
  const int sp0 = blockIdx.x * 64, b = blockIdx.z;
  const int rsel = lane >> 2;
  const int csw = (lane & 3) ^ ((lane >> 3) & 3);
  const us16* gAp0 = Wpb + (size_t)(16 * w + rsel) * 128 + csw * 8;
  const us16* gAq0 = Wqb + (size_t)(16 * w + rsel) * 128 + csw * 8;
  f32x4 accp[2][4] = {}, accq[2][4] = {};
  const int fr = lane & 15;
  const int kbA = 8 * ((lane >> 4) ^ ((lane >> 1) & 3));
  const int kbB = 8 * (lane >> 4);
  for (int c0 = 0; c0 < 128; c0 += 32) {
    gload16(gAp0 + c0, &Ap[0][16 * w][0]);
    gload16(gAp0 + 64 * 128 + c0, &Ap[1][16 * w][0]);
    gload16(gAq0 + c0, &Aq[0][16 * w][0]);
    gload16(gAq0 + 64 * 128 + c0, &Aq[1][16 * w][0]);
    for (int f = tid; f < 1024; f += TPB) {
      int cl = f >> 5, spp = f & 31;
      int c = c0 + cl;
      const us16* src = (c < 64) ? Frt : Fit;
      size_t addr = (size_t)(b * 64 + (c & 63)) * SP + sp0 + 2 * spp;
      unsigned v = *(const unsigned*)(src + addr);
      Bs[2 * spp][cl] = (us16)v;
      Bs[2 * spp + 1][cl] = (us16)(v >> 16);
    }
    __syncthreads();
    bf16x8 aP0 = *(const bf16x8*)&Ap[0][16 * w + fr][kbA];
    bf16x8 aP1 = *(const bf16x8*)&Ap[1][16 * w + fr][kbA];
    bf16x8 aQ0 = *(const bf16x8*)&Aq[0][16 * w + fr][kbA];
    bf16x8 aQ1 = *(const bf16x8*)&Aq[1][16 * w + fr][kbA];
#pragma unroll
    for (int t = 0; t < 4; ++t) {
      uint2 lo = *(const uint2*)&Bs[16 * t + fr][kbB];
      uint2 hi = *(const uint2*)&Bs[16 * t + fr][kbB + 4];
      uint4 qq; qq.x = lo.x; qq.y = lo.y; qq.z = hi.x; qq.w = hi.y;
      bf16x8 bb = *(const bf16x8*)&qq;
      accp[0][t] = MFMA(aP0, bb, accp[0][t], 0, 0, 0);
      accp[1][t] = MFMA(aP1, bb, accp[1][t], 0, 0, 0);
      accq[0][t] = MFMA(aQ0, bb, accq[0][t], 0, 0, 0);
      accq[1][t] = MFMA(aQ1, bb, accq[1][t], 0, 0, 0);
    }
    __syncthreads();
  }
#pragma unroll
  for (int t = 0; t < 4; ++t) {
    int sp = sp0 + 16 * t + fr;
#pragma unroll
    for (int ot = 0; ot < 2; ++ot)
#pragma unroll
      for (int j = 0; j < 4; ++j) {
        int o = ot * 64 + 16 * w + 4 * (lane >> 4) + j;
        size_t idx = (size_t)(b * 128 + o) * SP + sp;
        P[idx] = f2bf(accp[ot][t][j]);
        Q[idx] = f2bf(accq[ot][t][j]);
      }
  }
}

// ------- K3: H-DFT fwd, BOTH fu per block via rotation identity + fused GN stats -------
// Chains (fu0 tables): CP=C.P, SP=S.P, CQ=C.Q, SQ=S.Q (k=0..254; table zero at k=255)
// Y0[r]=CP+SQ+b, Y0[255-r]=CP-SQ+b
// E1 = cos_r*CP + sin_r*SP + cos_r*dP ; O1 = cos_r*SQ - sin_r*CQ - sin_r*dQ
// Y1[r]=E1+O1+b, Y1[255-r]=E1-O1+b   (dP=P[u][255]-P[u][0], dQ likewise)
__global__ __launch_bounds__(TPB) void k_dfth_fwd2(
    const us16* __restrict__ P, const us16* __restrict__ Q,
    const us16* __restrict__ CbA, const us16* __restrict__ SbA,
    const float* __restrict__ bias, const float* __restrict__ rot,
    us16* __restrict__ Yt0, us16* __restrict__ Yt1,
    float* __restrict__ gnpart) {
  __shared__ __align__(16) us16 Ac[2][2][64][32];
  __shared__ __align__(16) us16 As[2][2][64][32];
  __shared__ __align__(16) us16 Bp[2][64][32];
  __shared__ __align__(16) us16 Bq[2][64][32];
  const int tid = threadIdx.x, w = tid >> 6, lane = tid & 63;
  const int b = blockIdx.z;
  const int u0 = blockIdx.x * 64;
  const int rsel = lane >> 2;
  const int csw = (lane & 3) ^ ((lane >> 3) & 3);
  const us16* gAc = CbA + (((size_t)(16 * w + rsel)) << 8) + csw * 8;   // fu=0 tables
  const us16* gAs = SbA + (((size_t)(16 * w + rsel)) << 8) + csw * 8;
  const us16* gBp = P + (size_t)b * 128 * SP + (size_t)(u0 + 16 * w + rsel) * 256 + csw * 8;
  const us16* gBq = Q + (size_t)b * 128 * SP + (size_t)(u0 + 16 * w + rsel) * 256 + csw * 8;
  f32x4 cp[2][4] = {}, sq[2][4] = {}, sp_[2][4] = {}, cq[2][4] = {};
  const int fr = lane & 15;
  const int kb = 8 * ((lane >> 4) ^ ((lane >> 1) & 3));
#define STAGE_K3(pp, k0) do { \
    _Pragma("unroll") \
    for (int mt = 0; mt < 2; ++mt) { \
      gload16(gAc + (mt << 14) + (k0), &Ac[pp][mt][16 * w][0]); \
      gload16(gAs + (mt << 14) + (k0), &As[pp][mt][16 * w][0]); } \
    gload16(gBp + (k0), &Bp[pp][16 * w][0]); \
    gload16(gBq + (k0), &Bq[pp][16 * w][0]); } while (0)
  STAGE_K3(0, 0);
  int pp = 0;
  for (int k0 = 0; k0 < 256; k0 += 32) {
    if (k0 + 32 < 256) { STAGE_K3(pp ^ 1, k0 + 32); WAITVM(6); }
    else WAITVM(0);
    BAR_ACQ();
    bf16x8 aC[2], aS[2];
#pragma unroll
    for (int mt = 0; mt < 2; ++mt) {
      aC[mt] = *(const bf16x8*)&Ac[pp][mt][16 * w + fr][kb];
      aS[mt] = *(const bf16x8*)&As[pp][mt][16 * w + fr][kb];
    }
#pragma unroll
    for (int t = 0; t < 4; ++t) {
      bf16x8 bP = *(const bf16x8*)&Bp[pp][16 * t + fr][kb];
      bf16x8 bQ = *(const bf16x8*)&Bq[pp][16 * t + fr][kb];
#pragma unroll
      for (int mt = 0; mt < 2; ++mt) {
        cp[mt][t]  = MFMA(aC[mt], bP, cp[mt][t], 0, 0, 0);
        sp_[mt][t] = MFMA(aS[mt], bP, sp_[mt][t], 0, 0, 0);
        cq[mt][t]  = MFMA(aC[mt], bQ, cq[mt][t], 0, 0, 0);
        sq[mt][t]  = MFMA(aS[mt], bQ, sq[mt][t], 0, 0, 0);
      }
    }
    BAR_REL();
    pp ^= 1;
  }
  us16* yb0 = Yt0 + (size_t)b * 128 * SP;
  us16* yb1 = Yt1 + (size_t)b * 128 * SP;
  const us16* pb = P + (size_t)b * 128 * SP;
  const us16* qb = Q + (size_t)b * 128 * SP;
  const int mb_ = 16 * w + 4 * (lane >> 4);
  const int ub = (u0 / WF + 1) * WF;
  float rc[2][4], rs[2][4];
#pragma unroll
  for (int mt = 0; mt < 2; ++mt)
#pragma unroll
    for (int j = 0; j < 4; ++j) {
      int r = mt * 64 + mb_ + j;
      rc[mt][j] = rot[2 * r];
      rs[mt][j] = rot[2 * r + 1];
    }
  float s0f0 = 0.f, q0f0 = 0.f, s1f0 = 0.f, q1f0 = 0.f;
  float s0f1 = 0.f, q0f1 = 0.f, s1f1 = 0.f, q1f1 = 0.f;
#pragma unroll
  for (int t = 0; t < 4; ++t) {
    int u = u0 + 16 * t + fr;
    float bo = bias[u / WF];
    float dP = bf2f(pb[(size_t)u * 256 + 255]) - bf2f(pb[(size_t)u * 256]);
    float dQ = bf2f(qb[(size_t)u * 256 + 255]) - bf2f(qb[(size_t)u * 256]);
    float t0s = 0.f, t0q = 0.f, t1s = 0.f, t1q = 0.f;
#pragma unroll
    for (int mt = 0; mt < 2; ++mt) {
      int base = mt * 64 + mb_;
      float y0[4], z0[4], y1[4], z1[4];
#pragma unroll
      for (int j = 0; j < 4; ++j) {
        float CPv = cp[mt][t][j], SQv = sq[mt][t][j];
        float SPv = sp_[mt][t][j], CQv = cq[mt][t][j];
        y0[j] = CPv + SQv + bo;
        z0[j] = CPv - SQv + bo;
        float E1 = rc[mt][j] * (CPv + dP) + rs[mt][j] * SPv;
        float O1 = rc[mt][j] * SQv - rs[mt][j] * (CQv + dQ);
        y1[j] = E1 + O1 + bo;
        z1[j] = E1 - O1 + bo;
        t0s += y0[j]; t0q += y0[j] * y0[j];
        t1s += y1[j]; t1q += y1[j] * y1[j];
        if (base + j) {
          t0s += z0[j]; t0q += z0[j] * z0[j];
          t1s += z1[j]; t1q += z1[j] * z1[j];
        }
      }
      uint2 pk;
      pk.x = (unsigned)f2bf(y0[0]) | ((unsigned)f2bf(y0[1]) << 16);
      pk.y = (unsigned)f2bf(y0[2]) | ((unsigned)f2bf(y0[3]) << 16);
      *(uint2*)(yb0 + (size_t)u * 256 + base) = pk;
      pk.x = (unsigned)f2bf(z0[3]) | ((unsigned)f2bf(z0[2]) << 16);
      pk.y = (unsigned)f2bf(z0[1]) | ((unsigned)f2bf(z0[0]) << 16);
      *(uint2*)(yb0 + (size_t)u * 256 + 252 - base) = pk;
      pk.x = (unsigned)f2bf(y1[0]) | ((unsigned)f2bf(y1[1]) << 16);
      pk.y = (unsigned)f2bf(y1[2]) | ((unsigned)f2bf(y1[3]) << 16);
      *(uint2*)(yb1 + (size_t)u * 256 + base) = pk;
      pk.x = (unsigned)f2bf(z1[3]) | ((unsigned)f2bf(z1[2]) << 16);
      pk.y = (unsigned)f2bf(z1[1]) | ((unsigned)f2bf(z1[0]) << 16);
      *(uint2*)(yb1 + (size_t)u * 256 + 252 - base) = pk;
    }
    if (u >= ub) { s1f0 += t0s; q1f0 += t0q; s1f1 += t1s; q1f1 += t1q; }
    else { s0f0 += t0s; q0f0 += t0q; s0f1 += t1s; q0f1 += t1q; }
  }
  float* red = (float*)&Ac[0][0][0][0];   // reuse dead staging LDS (16KB >= 8KB)
  __syncthreads();
  red[tid] = s0f0; red[TPB + tid] = q0f0;
  red[2 * TPB + tid] = s1f0; red[3 * TPB + tid] = q1f0;
  red[4 * TPB + tid] = s0f1; red[5 * TPB + tid] = q0f1;
  red[6 * TPB + tid] = s1f1; red[7 * TPB + tid] = q1f1;
  __syncthreads();
  for (int st = TPB / 2; st > 0; st >>= 1) {
    if (tid < st) {
#pragma unroll
      for (int k = 0; k < 8; ++k) red[k * TPB + tid] += red[k * TPB + tid + st];
    }
    __syncthreads();
  }
  if (tid == 0) {
    float* gp0 = gnpart + ((size_t)b * NBX + blockIdx.x) * 4;
    float* gp1 = gnpart + (((size_t)gridDim.z + b) * NBX + blockIdx.x) * 4;
    gp0[0] = red[0]; gp0[1] = red[TPB];
    gp0[2] = red[2 * TPB]; gp0[3] = red[3 * TPB];
    gp1[0] = red[4 * TPB]; gp1[1] = red[5 * TPB];
    gp1[2] = red[6 * TPB]; gp1[3] = red[7 * TPB];
  }
}

// ---- K4: reduce fwd2 partials -> per-group stats (1 block per (b,g), parallel) ----
__global__ __launch_bounds__(TPB) void k_gn_stats2(const float* __restrict__ part,
                                                   float* __restrict__ stats) {
  const int bg = blockIdx.x, b = bg >> 4, g = bg & 15;
  const int tid = threadIdx.x;
  const int clo = g * 8, chi = clo + 8;
  float s = 0.f, ss = 0.f;
  for (int bx = tid; bx < NBX; bx += TPB) {
    int c0 = (bx * 64) / WF;
    int c1 = (bx * 64 + 63) / WF;
    const float* p = part + ((size_t)b * NBX + bx) * 4;
    if (c0 >= clo && c0 < chi) { s += p[0]; ss += p[1]; }
    if (c1 != c0 && c1 >= clo && c1 < chi) { s += p[2]; ss += p[3]; }
  }
  __shared__ float rs[TPB], rq[TPB];
  rs[tid] = s; rq[tid] = ss;
  __syncthreads();
  for (int st = TPB / 2; st > 0; st >>= 1) {
    if (tid < st) { rs[tid] += rs[tid + st]; rq[tid] += rq[tid + st]; }
    __syncthreads();
  }
  if (tid == 0) {
    const float inv = 1.f / (8.f * (float)HWF);
    float mean = rs[0] * inv;
    float var = rq[0] * inv - mean * mean;
    stats[bg * 2] = mean;
    stats[bg * 2 + 1] = rsqrtf(var + GN_EPS);
  }
}

// ------- K5: GN+ReLU + k-fold: Z+/- [b][u'][k=0..127] -------
__global__ __launch_bounds__(TPB) void k_gnfold(
    const us16* __restrict__ Yt, const float* __restrict__ stats,
    const float* __restrict__ gamma, const float* __restrict__ beta,
    us16* __restrict__ Zrp, us16* __restrict__ Zrm,
    us16* __restrict__ Zip, us16* __restrict__ Zim) {
  const int b = blockIdx.y;
  const int up = blockIdx.x * 8 + (threadIdx.x >> 5);   // 0..8255
  const int l32 = threadIdx.x & 31;
  const int c = up / WF;
  const int g1 = b * 16 + (c >> 3), g2 = g1 + 8;
  const float sc1 = gamma[c] * stats[g1 * 2 + 1];
  const float sh1 = beta[c] - stats[g1 * 2] * sc1;
  const float sc2 = gamma[64 + c] * stats[g2 * 2 + 1];
  const float sh2 = beta[64 + c] - stats[g2 * 2] * sc2;
  const us16* ybase = Yt + (size_t)b * 128 * SP;
  const us16* yr = ybase + (size_t)up * 256;
  const us16* yi = ybase + (size_t)(64 * WF + up) * 256;
  const int k0 = l32 * 4;
  uint2 ar = *(const uint2*)(yr + k0);
  uint2 mr = *(const uint2*)(yr + 252 - k0);
  uint2 ai = *(const uint2*)(yi + k0);
  uint2 mi = *(const uint2*)(yi + 252 - k0);
  us16 arv[4] = {(us16)ar.x, (us16)(ar.x >> 16), (us16)ar.y, (us16)(ar.y >> 16)};
  us16 mrv[4] = {(us16)mr.x, (us16)(mr.x >> 16), (us16)mr.y, (us16)(mr.y >> 16)};
  us16 aiv[4] = {(us16)ai.x, (us16)(ai.x >> 16), (us16)ai.y, (us16)(ai.y >> 16)};
  us16 miv[4] = {(us16)mi.x, (us16)(mi.x >> 16), (us16)mi.y, (us16)(mi.y >> 16)};
  us16 rp[4], rm[4], ip[4], im[4];
#pragma unroll
  for (int d = 0; d < 4; ++d) {
    float zr = fmaxf(bf2f(arv[d]) * sc1 + sh1, 0.f);
    float zi = fmaxf(bf2f(aiv[d]) * sc2 + sh2, 0.f);
    float pr = 0.f, pi = 0.f;
    if (k0 + d > 0) {
      pr = fmaxf(bf2f(mrv[3 - d]) * sc1 + sh1, 0.f);
      pi = fmaxf(bf2f(miv[3 - d]) * sc2 + sh2, 0.f);
    }
    rp[d] = f2bf(zr + pr); rm[d] = f2bf(zr - pr);
    ip[d] = f2bf(zi + pi); im[d] = f2bf(zi - pi);
  }
  const size_t zo = ((size_t)b * UZ + up) * 128 + k0;
  uint2 o1; o1.x = (unsigned)rp[0] | ((unsigned)rp[1] << 16);
  o1.y = (unsigned)rp[2] | ((unsigned)rp[3] << 16);
  *(uint2*)(Zrp + zo) = o1;
  uint2 o2; o2.x = (unsigned)rm[0] | ((unsigned)rm[1] << 16);
  o2.y = (unsigned)rm[2] | ((unsigned)rm[3] << 16);
  *(uint2*)(Zrm + zo) = o2;
  uint2 o3; o3.x = (unsigned)ip[0] | ((unsigned)ip[1] << 16);
  o3.y = (unsigned)ip[2] | ((unsigned)ip[3] << 16);
  *(uint2*)(Zip + zo) = o3;
  uint2 o4; o4.x = (unsigned)im[0] | ((unsigned)im[1] << 16);
  o4.y = (unsigned)im[2] | ((unsigned)im[3] << 16);
  *(uint2*)(Zim + zo) = o4;
}

// ------- K6: inverse H-DFT, K folded to 128 -> Hr/Hi bf16 [bc*128+m][160] -------
__global__ __launch_bounds__(TPB) void k_dfth_inv_mfma(
    const us16* __restrict__ Zrp, const us16* __restrict__ Zrm,
    const us16* __restrict__ Zip, const us16* __restrict__ Zim,
    const us16* __restrict__ CbA, const us16* __restrict__ SbA,
    us16* __restrict__ Hr, us16* __restrict__ Hi, int hsel) {
  __shared__ __align__(16) us16 Ac[2][2][64][32];
  __shared__ __align__(16) us16 As[2][2][64][32];
  __shared__ __align__(16) us16 Brp[2][64][32];
  __shared__ __align__(16) us16 Brm[2][64][32];
  __shared__ __align__(16) us16 Bip[2][64][32];
  __shared__ __align__(16) us16 Bim[2][64][32];
  const int tid = threadIdx.x, w = tid >> 6, lane = tid & 63;
  const int b = blockIdx.z;
  const int u0 = blockIdx.x * 64;
  const int rsel = lane >> 2;
  const int csw = (lane & 3) ^ ((lane >> 3) & 3);
  const us16* gAc = CbA + (((size_t)hsel + 16 * w + rsel) << 8) + csw * 8;
  const us16* gAs = SbA + (((size_t)hsel + 16 * w + rsel) << 8) + csw * 8;
  const size_t zoff = ((size_t)b * UZ + u0 + 16 * w + rsel) * 128 + csw * 8;
  const us16* gZrp = Zrp + zoff;
  const us16* gZrm = Zrm + zoff;
  const us16* gZip = Zip + zoff;
  const us16* gZim = Zim + zoff;
  f32x4 accr[2][4] = {}, acci[2][4] = {};
  const int fr = lane & 15;
  const int kb = 8 * ((lane >> 4) ^ ((lane >> 1) & 3));
#define STAGE_K6(pp, k0) do { \
    gload16(gAc + (k0), &Ac[pp][0][16 * w][0]); \
    gload16(gAc + (1 << 14) + (k0), &Ac[pp][1][16 * w][0]); \
    gload16(gAs + (k0), &As[pp][0][16 * w][0]); \
    gload16(gAs + (1 << 14) + (k0), &As[pp][1][16 * w][0]); \
    gload16(gZrp + (k0), &Brp[pp][16 * w][0]); \
    gload16(gZrm + (k0), &Brm[pp][16 * w][0]); \
    gload16(gZip + (k0), &Bip[pp][16 * w][0]); \
    gload16(gZim + (k0), &Bim[pp][16 * w][0]); } while (0)
  STAGE_K6(0, 0);
  int pp = 0;
  for (int k0 = 0; k0 < 128; k0 += 32) {
    if (k0 + 32 < 128) { STAGE_K6(pp ^ 1, k0 + 32); WAITVM(8); }
    else WAITVM(0);
    BAR_ACQ();
    bf16x8 aC[2], aS[2], aSn[2];
#pragma unroll
    for (int mt = 0; mt < 2; ++mt) {
      aC[mt] = *(const bf16x8*)&Ac[pp][mt][16 * w + fr][kb];
      aS[mt] = *(const bf16x8*)&As[pp][mt][16 * w + fr][kb];
      uint4 su = *(const uint4*)&aS[mt];
      su.x ^= 0x80008000u; su.y ^= 0x80008000u; su.z ^= 0x80008000u; su.w ^= 0x80008000u;
      aSn[mt] = *(const bf16x8*)&su;
    }
#pragma unroll
    for (int t = 0; t < 4; ++t) {
      bf16x8 bRp = *(const bf16x8*)&Brp[pp][16 * t + fr][kb];
      bf16x8 bRm = *(const bf16x8*)&Brm[pp][16 * t + fr][kb];
      bf16x8 bIp = *(const bf16x8*)&Bip[pp][16 * t + fr][kb];
      bf16x8 bIm = *(const bf16x8*)&Bim[pp][16 * t + fr][kb];
#pragma unroll
      for (int mt = 0; mt < 2; ++mt) {
        accr[mt][t] = MFMA(aC[mt], bRp, accr[mt][t], 0, 0, 0);
        accr[mt][t] = MFMA(aSn[mt], bIm, accr[mt][t], 0, 0, 0);
        acci[mt][t] = MFMA(aC[mt], bIp, acci[mt][t], 0, 0, 0);
        acci[mt][t] = MFMA(aS[mt], bRm, acci[mt][t], 0, 0, 0);
      }
    }
    BAR_REL();
    pp ^= 1;
  }
  const float inv = 1.f / 255.f;
#pragma unroll
  for (int t = 0; t < 4; ++t) {
    int u = u0 + 16 * t + fr;
    int c = u / WF, n = u - c * WF;
#pragma unroll
    for (int mt = 0; mt < 2; ++mt) {
#pragma unroll
      for (int j = 0; j < 4; ++j) {
        int m = mt * 64 + 16 * w + 4 * (lane >> 4) + j;
        size_t idx = (((size_t)(b * 64 + c)) * 128 + m) * KH + n;
        Hr[idx] = f2bf(accr[mt][t][j] * inv);
        Hi[idx] = f2bf(acci[mt][t][j] * inv);
      }
    }
  }
}

// ------- K7: inverse W-DFT, W-symmetric (w=0..127 -> cols w and 256-w) -------
__global__ __launch_bounds__(TPB) void k_dftw_inv_mfma(
    const us16* __restrict__ Hr, const us16* __restrict__ Hi,
    const us16* __restrict__ Tci, const us16* __restrict__ Tsi,
    float* __restrict__ out, int roff, int b0) {
  __shared__ __align__(16) us16 Ar[2][64][32];
  __shared__ __align__(16) us16 Ai[2][64][32];
  __shared__ __align__(16) us16 Bc[2][64][32];
  __shared__ __align__(16) us16 Bs[2][64][32];
  const int tid = threadIdx.x, w = tid >> 6, lane = tid & 63;
  const int w0 = blockIdx.x * 64, mf0 = blockIdx.y * 64;
  const int rsel = lane >> 2;
  const int csw = (lane & 3) ^ ((lane >> 3) & 3);
  const us16* gAr = Hr + (size_t)(mf0 + 16 * w + rsel) * KH + csw * 8;
  const us16* gAi = Hi + (size_t)(mf0 + 16 * w + rsel) * KH + csw * 8;
  const us16* gBc = Tci + (size_t)(w0 + 16 * w + rsel) * KH + csw * 8;
  const us16* gBs = Tsi + (size_t)(w0 + 16 * w + rsel) * KH + csw * 8;
  f32x4 accU[4] = {}, accV[4] = {};
  const int fr = lane & 15;
  const int kb = 8 * ((lane >> 4) ^ ((lane >> 1) & 3));
#define STAGE_K7(pp, k0) do { \
    gload16(gAr + (k0), &Ar[pp][16 * w][0]); \
    gload16(gAi + (k0), &Ai[pp][16 * w][0]); \
    gload16(gBc + (k0), &Bc[pp][16 * w][0]); \
    gload16(gBs + (k0), &Bs[pp][16 * w][0]); } while (0)
  STAGE_K7(0, 0);
  int pp = 0;
  for (int k0 = 0; k0 < KH; k0 += 32) {
    if (k0 + 32 < KH) { STAGE_K7(pp ^ 1, k0 + 32); WAITVM(4); }
    else WAITVM(0);
    BAR_ACQ();
    bf16x8 aR = *(const bf16x8*)&Ar[pp][16 * w + fr][kb];
    bf16x8 aI = *(const bf16x8*)&Ai[pp][16 * w + fr][kb];
    uint4 su = *(const uint4*)&aI;
    su.x ^= 0x80008000u; su.y ^= 0x80008000u; su.z ^= 0x80008000u; su.w ^= 0x80008000u;
    bf16x8 aIn = *(const bf16x8*)&su;
#pragma unroll
    for (int t = 0; t < 4; ++t) {
      bf16x8 bC = *(const bf16x8*)&Bc[pp][16 * t + fr][kb];
      bf16x8 bS = *(const bf16x8*)&Bs[pp][16 * t + fr][kb];
      accU[t] = MFMA(aR, bC, accU[t], 0, 0, 0);
      accV[t] = MFMA(aIn, bS, accV[t], 0, 0, 0);
    }
    BAR_REL();
    pp ^= 1;
  }
#pragma unroll
  for (int t = 0; t < 4; ++t) {
    int wv = w0 + 16 * t + fr;                 // 0..127
#pragma unroll
    for (int j = 0; j < 4; ++j) {
      int mf = mf0 + 16 * w + 4 * (lane >> 4) + j;
      int bcl = mf >> 7, mrow = mf & 127;
      int bb = b0 + (bcl >> 6), cc = bcl & 63;
      size_t obase = (((size_t)bb * CH + cc) * HIN + roff + mrow) * WIN;
      float U = accU[t][j], V = accV[t][j];
      out[obase + wv] = U + V;
      if (wv > 0) out[obase + 256 - wv] = U - V;
    }
  }
}

// ------- K8: missing column w=128 (sin==0): alternating sum of Hr -------
__global__ __launch_bounds__(TPB) void k_w128(const us16* __restrict__ Hr,
                                              float* __restrict__ out,
                                              int roff, int b0) {
  const int mf = blockIdx.x * TPB + threadIdx.x;
  const us16* hr = Hr + (size_t)mf * KH;
  float s = bf2f(hr[0]) + bf2f(hr[128]);
  for (int k = 1; k < 128; k += 2)
    s += -2.f * bf2f(hr[k]) + 2.f * bf2f(hr[k + 1]);
  s -= 2.f * bf2f(hr[128]);
  s *= (1.f / 256.f);
  int bcl = mf >> 7, mrow = mf & 127;
  int bb = b0 + (bcl >> 6), cc = bcl & 63;
  out[(((size_t)bb * CH + cc) * HIN + roff + mrow) * WIN + 128] = s;
}

// ---------------- host ----------------
extern "C" void kernel_launch(void* const* d_in, const int* in_sizes, int n_in,
                              void* d_out, int out_size, void* d_ws, size_t ws_size,
                              hipStream_t stream) {
  const float* x        = (const float*)d_in[0];
  const float* conv_w   = (const float*)d_in[1];
  const float* conv_b   = (const float*)d_in[2];
  const float* gn_gamma = (const float*)d_in[3];
  const float* gn_beta  = (const float*)d_in[4];
  float* out = (float*)d_out;

  // u16 units
  const size_t uCbA = 2 * 65536;
  const size_t uTcb = 128 * 256;
  const size_t uTci = (size_t)256 * KH;
  const size_t uW   = 128 * 128;
  const size_t fixed_u16 = 2 * uCbA + 2 * uTcb + 2 * uTci + 2 * uW;
  const size_t uXB = (size_t)CH * HIN * WIN;      // 4194304
  const size_t uF  = (size_t)CH * SP;             // 2113536
  const size_t uPQ = (size_t)128 * SP;            // 4227072
  const size_t uYT = (size_t)128 * SP;            // 4227072
  const size_t uH  = (size_t)CH * 128 * KH;       // 1310720
  const size_t uZ1 = (size_t)UZ * 128;            // 1056768 per Z array
  const size_t per_u16 = uXB + 2 * uF + 2 * uPQ + 4 * uZ1 + uYT;  // + Yt1
  const size_t nPart = 2 * 4 * NBX * 4 + 256 + 256;

  int nb = 0;
  for (int cand = 4; cand >= 1; cand >>= 1) {
    size_t need = fixed_u16 * 2 + nPart * 4 + (size_t)cand * per_u16 * 2 + 256;
    if (need <= ws_size) { nb = cand; break; }
  }
  if (nb == 0) {
    k_zero<<<dim3((out_size + TPB - 1) / TPB), dim3(TPB), 0, stream>>>(out, out_size);
    return;
  }

  us16* CbA = (us16*)d_ws;
  us16* SbA = CbA + uCbA;
  us16* Tcb = SbA + uCbA;
  us16* Tsb = Tcb + uTcb;
  us16* Tci = Tsb + uTcb;
  us16* Tsi = Tci + uTci;
  us16* Wpb = Tsi + uTci;
  us16* Wqb = Wpb + uW;
  float* part  = (float*)(Wqb + uW);      // [fu][b][NBX][4]
  float* stats = part + 2 * 4 * NBX * 4;  // [fu][b*16][2]
  float* rot   = stats + 256;
  us16* xb  = (us16*)(rot + 256);
  us16* Frt = xb + (size_t)nb * uXB;
  us16* Fit = Frt + (size_t)nb * uF;
  us16* P   = Fit + (size_t)nb * uF;
  us16* Q   = P + (size_t)nb * uPQ;
  us16* Zrp = Q + (size_t)nb * uPQ;
  us16* Zrm = Zrp + (size_t)nb * uZ1;
  us16* Zip = Zrm + (size_t)nb * uZ1;
  us16* Zim = Zip + (size_t)nb * uZ1;
  us16* Yt1 = Zim + (size_t)nb * uZ1;
  // aliases into [xb | Frt | Fit] (dead after k_mix): Yt0 then Hr/Hi
  us16* Yt0 = xb;
  us16* Hr  = xb + (size_t)nb * uYT;
  us16* Hi  = Hr + (size_t)nb * uH;

  k_tables<<<dim3(512), dim3(TPB), 0, stream>>>(CbA, SbA, Tcb, Tsb, Tci, Tsi,
                                                Wpb, Wqb, rot, conv_w);

  for (int b0 = 0; b0 < B_ALL; b0 += nb) {
    k_xcast2<<<dim3(nb * 4096), dim3(TPB), 0, stream>>>(
        x + (size_t)b0 * CH * HIN * WIN, xb, Frt, Fit);
    k_dftw_fwd_mfma<<<dim3(nb * 256), dim3(TPB), 0, stream>>>(
        xb, Tcb, Tsb, Frt, Fit);
    k_mix<<<dim3(SP / 64, 1, nb), dim3(TPB), 0, stream>>>(
        Frt, Fit, Wpb, Wqb, P, Q);
    k_dfth_fwd2<<<dim3(NBX, 1, nb), dim3(TPB), 0, stream>>>(
        P, Q, CbA, SbA, conv_b, rot, Yt0, Yt1, part);
    for (int fu = 0; fu < 2; ++fu) {
      const int hsel = fu ? 127 : 0;
      const int roff = fu ? 128 : 0;
      const us16* Yt = fu ? Yt1 : Yt0;
      float* pfu = part + (size_t)fu * nb * NBX * 4;
      float* sfu = stats + (size_t)fu * nb * 32;
      k_gn_stats2<<<dim3(nb * 16), dim3(TPB), 0, stream>>>(pfu, sfu);
      k_gnfold<<<dim3(UZ / 8, nb), dim3(TPB), 0, stream>>>(
          Yt, sfu, gn_gamma, gn_beta, Zrp, Zrm, Zip, Zim);
      k_dfth_inv_mfma<<<dim3(UZ / 64, 1, nb), dim3(TPB), 0, stream>>>(
          Zrp, Zrm, Zip, Zim, CbA, SbA, Hr, Hi, hsel);
      k_dftw_inv_mfma<<<dim3(2, nb * 128), dim3(TPB), 0, stream>>>(
          Hr, Hi, Tci, Tsi, out, roff, b0);
      k_w128<<<dim3(nb * 32), dim3(TPB), 0, stream>>>(Hr, out, roff, b0);
    }
  }
}

// Round 20
// 248.412 us; speedup vs baseline: 1.0472x; 1.0472x over previous
//
#include <hip/hip_runtime.h>
#include <math.h>

#define TPB 256

typedef unsigned short us16;
typedef __bf16 bf16x8 __attribute__((ext_vector_type(8)));
typedef float f32x4 __attribute__((ext_vector_type(4)));

static const int B_ALL = 4;
static const int CH   = 64;
static const int HIN  = 256, WIN = 256;
static const int HH   = 255;
static const int WF   = 129;          // valid n per channel
static const int HWF  = HH * WF;      // 32895 valid GN count per channel
static const int SP   = WF * 256;     // 33024 packed spatial per channel
static const int KH   = 160;          // padded K for inverse W-DFT
static const int UZ   = 64 * WF;      // 8256 packed (c,n) rows per batch (inv side)
static const int NBX  = 258;          // fwd2 blocks per batch (128*129/64)
#define GN_EPS 1e-5f

__device__ __forceinline__ us16 f2bf(float f) {
  union { float f; unsigned u; } v; v.f = f;
  unsigned r = v.u + 0x7FFFu + ((v.u >> 16) & 1u);
  return (us16)(r >> 16);
}
__device__ __forceinline__ float bf2f(us16 v) {
  union { unsigned u; float f; } t; t.u = ((unsigned)v) << 16; return t.f;
}
__device__ __forceinline__ void gload16(const void* g, void* l) {
  __builtin_amdgcn_global_load_lds(
      (const __attribute__((address_space(1))) unsigned int*)g,
      (__attribute__((address_space(3))) unsigned int*)l, 16, 0, 0);
}
#define MFMA __builtin_amdgcn_mfma_f32_16x16x32_bf16
#define WAITVM(N) asm volatile("s_waitcnt vmcnt(" #N ")" ::: "memory")
#define BAR_ACQ() do { \
    __builtin_amdgcn_s_barrier(); \
    asm volatile("" ::: "memory"); \
    __builtin_amdgcn_sched_barrier(0); } while (0)
#define BAR_REL() do { \
    asm volatile("" ::: "memory"); \
    __builtin_amdgcn_s_barrier(); } while (0)

// ---------------- fallback ----------------
__global__ __launch_bounds__(TPB) void k_zero(float* __restrict__ out, int n) {
  int i = blockIdx.x * TPB + threadIdx.x;
  if (i < n) out[i] = 0.f;
}

// ---- cast x f32->bf16 (one wave per row) + analytic Nyquist bin n=128 ----
__global__ __launch_bounds__(TPB) void k_xcast2(const float* __restrict__ x,
                                                us16* __restrict__ xb,
                                                us16* __restrict__ Frt,
                                                us16* __restrict__ Fit) {
  const int row = blockIdx.x * 4 + (threadIdx.x >> 6);
  const int lane = threadIdx.x & 63;
  float4 v = ((const float4*)(x + (size_t)row * 256))[lane];
  ushort4 o;
  o.x = f2bf(v.x); o.y = f2bf(v.y); o.z = f2bf(v.z); o.w = f2bf(v.w);
  ((ushort4*)(xb + (size_t)row * 256))[lane] = o;
  float alt = v.x - v.y + v.z - v.w;
  for (int off = 32; off; off >>= 1) alt += __shfl_down(alt, off);
  if (lane == 0) {
    int bc = row >> 8, h = row & 255;
    size_t idx = ((size_t)bc * WF + 128) * 256 + h;
    Frt[idx] = f2bf(alt);
    Fit[idx] = 0;
  }
}

// ---------------- bf16 tables ----------------
__global__ __launch_bounds__(TPB) void k_tables(
    us16* __restrict__ CbA, us16* __restrict__ SbA,
    us16* __restrict__ Tcb, us16* __restrict__ Tsb,
    us16* __restrict__ Tci, us16* __restrict__ Tsi,
    us16* __restrict__ Wpb, us16* __restrict__ Wqb,
    const float* __restrict__ conv_w) {
  int i = blockIdx.x * TPB + threadIdx.x;
  const double PI2 = 6.283185307179586476925286766559;
  if (i < 2 * 65536) {                      // H-DFT [fu][r][k], k-shift absorbed
    int fu = i >> 16, r = (i >> 8) & 255, k = i & 255;
    float cv = 0.f, sv = 0.f;
    int kk = k - fu;
    if (r < 255 && kk >= 0 && kk < 255) {
      double ang = PI2 * (double)((r * kk) % 255) / 255.0;
      cv = (float)cos(ang); sv = (float)sin(ang);
    }
    CbA[i] = f2bf(cv); SbA[i] = f2bf(sv);
  }
  if (i < 128 * 256) {                      // W-DFT fwd transposed [n<128][w]
    int n = i >> 8, w = i & 255;
    double ang = PI2 * (double)((n * w) & 255) / 256.0;
    Tcb[i] = f2bf((float)cos(ang));
    Tsb[i] = f2bf((float)sin(ang));
  }
  if (i < 256 * KH) {                       // W-DFT inv [w][k], Hermitian coef
    int w = i / KH, k = i - w * KH;
    float cv = 0.f, sv = 0.f;
    if (k < WF) {
      double coef = (k == 0 || k == 128) ? 1.0 : 2.0;
      double ang = PI2 * (double)((k * w) & 255) / 256.0;
      cv = (float)(coef * cos(ang) / 256.0);
      sv = (float)(coef * sin(ang) / 256.0);
    }
    Tci[i] = f2bf(cv); Tsi[i] = f2bf(sv);
  }
  if (i < 128 * 128) {                      // mix weights
    int o = i >> 7, c = i & 127;
    Wpb[i] = f2bf(conv_w[i]);
    float q = (c < 64) ? -conv_w[o * 128 + 64 + c] : conv_w[o * 128 + c - 64];
    Wqb[i] = f2bf(q);
  }
}

// ------- K1: forward W-DFT, BOTH n-halves per block (B staged once) -------
__global__ __launch_bounds__(TPB) void k_dftw_fwd_mfma(
    const us16* __restrict__ xb, const us16* __restrict__ Tcb,
    const us16* __restrict__ Tsb, us16* __restrict__ Frt, us16* __restrict__ Fit) {
  __shared__ __align__(16) us16 Ac[2][2][64][32];   // [pp][half]
  __shared__ __align__(16) us16 As[2][2][64][32];
  __shared__ __align__(16) us16 Bx[2][64][32];
  const int tid = threadIdx.x, w = tid >> 6, lane = tid & 63;
  const int hb = blockIdx.x;
  const int rsel = lane >> 2;
  const int csw = (lane & 3) ^ ((lane >> 3) & 3);
  const us16* gAc = Tcb + (size_t)(16 * w + rsel) * 256 + csw * 8;
  const us16* gAs = Tsb + (size_t)(16 * w + rsel) * 256 + csw * 8;
  const us16* gB  = xb + ((size_t)hb * 64 + 16 * w + rsel) * 256 + csw * 8;
  f32x4 accr[2][4] = {}, acci[2][4] = {};
  const int fr = lane & 15;
  const int kb = 8 * ((lane >> 4) ^ ((lane >> 1) & 3));
#define STAGE_K1(pp, k0) do { \
    gload16(gAc + (k0), &Ac[pp][0][16 * w][0]); \
    gload16(gAc + 64 * 256 + (k0), &Ac[pp][1][16 * w][0]); \
    gload16(gAs + (k0), &As[pp][0][16 * w][0]); \
    gload16(gAs + 64 * 256 + (k0), &As[pp][1][16 * w][0]); \
    gload16(gB + (k0), &Bx[pp][16 * w][0]); } while (0)
  STAGE_K1(0, 0);
  int pp = 0;
  for (int k0 = 0; k0 < 256; k0 += 32) {
    if (k0 + 32 < 256) { STAGE_K1(pp ^ 1, k0 + 32); WAITVM(5); }
    else WAITVM(0);
    BAR_ACQ();
    bf16x8 aC[2], aSn[2];
#pragma unroll
    for (int g = 0; g < 2; ++g) {
      aC[g] = *(const bf16x8*)&Ac[pp][g][16 * w + fr][kb];
      bf16x8 aS = *(const bf16x8*)&As[pp][g][16 * w + fr][kb];
      uint4 su = *(const uint4*)&aS;
      su.x ^= 0x80008000u; su.y ^= 0x80008000u; su.z ^= 0x80008000u; su.w ^= 0x80008000u;
      aSn[g] = *(const bf16x8*)&su;
    }
#pragma unroll
    for (int t = 0; t < 4; ++t) {
      bf16x8 b = *(const bf16x8*)&Bx[pp][16 * t + fr][kb];
#pragma unroll
      for (int g = 0; g < 2; ++g) {
        accr[g][t] = MFMA(aC[g], b, accr[g][t], 0, 0, 0);
        acci[g][t] = MFMA(aSn[g], b, acci[g][t], 0, 0, 0);
      }
    }
    BAR_REL();
    pp ^= 1;
  }
  const int bc = hb >> 2, hl = (hb & 3) * 64;
#pragma unroll
  for (int g = 0; g < 2; ++g) {
#pragma unroll
    for (int t = 0; t < 4; ++t) {
      int h = hl + 16 * t + fr;
#pragma unroll
      for (int j = 0; j < 4; ++j) {
        int n = g * 64 + 16 * w + 4 * (lane >> 4) + j;
        size_t idx = ((size_t)bc * WF + n) * 256 + h;
        Frt[idx] = f2bf(accr[g][t][j]);
        Fit[idx] = f2bf(acci[g][t][j]);
      }
    }
  }
}

// ------- K2: channel-mix, BOTH o-tiles per block (B staged once) -------
__global__ __launch_bounds__(TPB) void k_mix(
    const us16* __restrict__ Frt, const us16* __restrict__ Fit,
    const us16* __restrict__ Wpb, const us16* __restrict__ Wqb,
    us16* __restrict__ P, us16* __restrict__ Q) {
  __shared__ __align__(16) us16 Ap[2][64][32];
  __shared__ __align__(16) us16 Aq[2][64][32];
  __shared__ __align__(8)  us16 Bs[64][36];
  const int tid = threadIdx.x, w = tid >> 6, lane = tid & 63;
  const int sp0 = blockIdx.x * 64, b = blockIdx.z;
  const int rsel = lane >> 2;
  const int csw = (lane & 3) ^ ((lane >> 3) & 3);
  const us16* gAp0 = Wpb + (size_t)(16 * w + rsel) * 128 + csw * 8;
  const us16* gAq0 = Wqb + (size_t)(16 * w + rsel) * 128 + csw * 8;
  f32x4 accp[2][4] = {}, accq[2][4] = {};
  const int fr = lane & 15;
  const int kbA = 8 * ((lane >> 4) ^ ((lane >> 1) & 3));
  const int kbB = 8 * (lane >> 4);
  for (int c0 = 0; c0 < 128; c0 += 32) {
    gload16(gAp0 + c0, &Ap[0][16 * w][0]);
    gload16(gAp0 + 64 * 128 + c0, &Ap[1][16 * w][0]);
    gload16(gAq0 + c0, &Aq[0][16 * w][0]);
    gload16(gAq0 + 64 * 128 + c0, &Aq[1][16 * w][0]);
    for (int f = tid; f < 1024; f += TPB) {
      int cl = f >> 5, spp = f & 31;
      int c = c0 + cl;
      const us16* src = (c < 64) ? Frt : Fit;
      size_t addr = (size_t)(b * 64 + (c & 63)) * SP + sp0 + 2 * spp;
      unsigned v = *(const unsigned*)(src + addr);
      Bs[2 * spp][cl] = (us16)v;
      Bs[2 * spp + 1][cl] = (us16)(v >> 16);
    }
    __syncthreads();
    bf16x8 aP0 = *(const bf16x8*)&Ap[0][16 * w + fr][kbA];
    bf16x8 aP1 = *(const bf16x8*)&Ap[1][16 * w + fr][kbA];
    bf16x8 aQ0 = *(const bf16x8*)&Aq[0][16 * w + fr][kbA];
    bf16x8 aQ1 = *(const bf16x8*)&Aq[1][16 * w + fr][kbA];
#pragma unroll
    for (int t = 0; t < 4; ++t) {
      uint2 lo = *(const uint2*)&Bs[16 * t + fr][kbB];
      uint2 hi = *(const uint2*)&Bs[16 * t + fr][kbB + 4];
      uint4 qq; qq.x = lo.x; qq.y = lo.y; qq.z = hi.x; qq.w = hi.y;
      bf16x8 bb = *(const bf16x8*)&qq;
      accp[0][t] = MFMA(aP0, bb, accp[0][t], 0, 0, 0);
      accp[1][t] = MFMA(aP1, bb, accp[1][t], 0, 0, 0);
      accq[0][t] = MFMA(aQ0, bb, accq[0][t], 0, 0, 0);
      accq[1][t] = MFMA(aQ1, bb, accq[1][t], 0, 0, 0);
    }
    __syncthreads();
  }
#pragma unroll
  for (int t = 0; t < 4; ++t) {
    int sp = sp0 + 16 * t + fr;
#pragma unroll
    for (int ot = 0; ot < 2; ++ot)
#pragma unroll
      for (int j = 0; j < 4; ++j) {
        int o = ot * 64 + 16 * w + 4 * (lane >> 4) + j;
        size_t idx = (size_t)(b * 128 + o) * SP + sp;
        P[idx] = f2bf(accp[ot][t][j]);
        Q[idx] = f2bf(accq[ot][t][j]);
      }
  }
}

// ------- K3: H-DFT fwd, M-symmetric + fused GN partial stats (64-wide u-tiles) -------
__global__ __launch_bounds__(TPB) void k_dfth_fwd2(
    const us16* __restrict__ P, const us16* __restrict__ Q,
    const us16* __restrict__ CbA, const us16* __restrict__ SbA,
    const float* __restrict__ bias, us16* __restrict__ Yt,
    float* __restrict__ gnpart, int fu) {
  __shared__ __align__(16) us16 Ac[2][2][64][32];
  __shared__ __align__(16) us16 As[2][2][64][32];
  __shared__ __align__(16) us16 Bp[2][64][32];
  __shared__ __align__(16) us16 Bq[2][64][32];
  __shared__ float red[4 * TPB];
  const int tid = threadIdx.x, w = tid >> 6, lane = tid & 63;
  const int b = blockIdx.z;
  const int u0 = blockIdx.x * 64;
  const int rsel = lane >> 2;
  const int csw = (lane & 3) ^ ((lane >> 3) & 3);
  const us16* gAc = CbA + (((size_t)fu * 256 + 16 * w + rsel) << 8) + csw * 8;
  const us16* gAs = SbA + (((size_t)fu * 256 + 16 * w + rsel) << 8) + csw * 8;
  const us16* gBp = P + (size_t)b * 128 * SP + (size_t)(u0 + 16 * w + rsel) * 256 + csw * 8;
  const us16* gBq = Q + (size_t)b * 128 * SP + (size_t)(u0 + 16 * w + rsel) * 256 + csw * 8;
  f32x4 cp[2][4] = {}, sq[2][4] = {};
  const int fr = lane & 15;
  const int kb = 8 * ((lane >> 4) ^ ((lane >> 1) & 3));
#define STAGE_K3(pp, k0) do { \
    _Pragma("unroll") \
    for (int mt = 0; mt < 2; ++mt) { \
      gload16(gAc + (mt << 14) + (k0), &Ac[pp][mt][16 * w][0]); \
      gload16(gAs + (mt << 14) + (k0), &As[pp][mt][16 * w][0]); } \
    gload16(gBp + (k0), &Bp[pp][16 * w][0]); \
    gload16(gBq + (k0), &Bq[pp][16 * w][0]); } while (0)
  STAGE_K3(0, 0);
  int pp = 0;
  for (int k0 = 0; k0 < 256; k0 += 32) {
    if (k0 + 32 < 256) { STAGE_K3(pp ^ 1, k0 + 32); WAITVM(6); }
    else WAITVM(0);
    BAR_ACQ();
    bf16x8 aC[2], aS[2];
#pragma unroll
    for (int mt = 0; mt < 2; ++mt) {
      aC[mt] = *(const bf16x8*)&Ac[pp][mt][16 * w + fr][kb];
      aS[mt] = *(const bf16x8*)&As[pp][mt][16 * w + fr][kb];
    }
#pragma unroll
    for (int t = 0; t < 4; ++t) {
      bf16x8 bP = *(const bf16x8*)&Bp[pp][16 * t + fr][kb];
      bf16x8 bQ = *(const bf16x8*)&Bq[pp][16 * t + fr][kb];
#pragma unroll
      for (int mt = 0; mt < 2; ++mt) {
        cp[mt][t] = MFMA(aC[mt], bP, cp[mt][t], 0, 0, 0);
        sq[mt][t] = MFMA(aS[mt], bQ, sq[mt][t], 0, 0, 0);
      }
    }
    BAR_REL();
    pp ^= 1;
  }
  us16* yb = Yt + (size_t)b * 128 * SP;
  const int mb_ = 16 * w + 4 * (lane >> 4);
  const int ub = (u0 / WF + 1) * WF;           // first u of bucket-1 channel
  float s0 = 0.f, q0 = 0.f, s1 = 0.f, q1 = 0.f;
#pragma unroll
  for (int t = 0; t < 4; ++t) {
    int u = u0 + 16 * t + fr;
    float bo = bias[u / WF];
    float ts = 0.f, tq = 0.f;
#pragma unroll
    for (int mt = 0; mt < 2; ++mt) {
      int base = mt * 64 + mb_;                // r = base + j, 0..127
      float y[4], z[4];
#pragma unroll
      for (int j = 0; j < 4; ++j) {
        y[j] = cp[mt][t][j] + sq[mt][t][j] + bo; // row r
        z[j] = cp[mt][t][j] - sq[mt][t][j] + bo; // row 255-r
        ts += y[j]; tq += y[j] * y[j];
        if (base + j) { ts += z[j]; tq += z[j] * z[j]; }  // skip m==255 pad
      }
      uint2 pk;
      pk.x = (unsigned)f2bf(y[0]) | ((unsigned)f2bf(y[1]) << 16);
      pk.y = (unsigned)f2bf(y[2]) | ((unsigned)f2bf(y[3]) << 16);
      *(uint2*)(yb + (size_t)u * 256 + base) = pk;
      uint2 pk2;                               // reversed: m' = 252-base .. 255-base
      pk2.x = (unsigned)f2bf(z[3]) | ((unsigned)f2bf(z[2]) << 16);
      pk2.y = (unsigned)f2bf(z[1]) | ((unsigned)f2bf(z[0]) << 16);
      *(uint2*)(yb + (size_t)u * 256 + 252 - base) = pk2;
    }
    if (u >= ub) { s1 += ts; q1 += tq; } else { s0 += ts; q0 += tq; }
  }
  __syncthreads();
  red[tid] = s0; red[TPB + tid] = q0;
  red[2 * TPB + tid] = s1; red[3 * TPB + tid] = q1;
  __syncthreads();
  for (int st = TPB / 2; st > 0; st >>= 1) {
    if (tid < st) {
      red[tid] += red[tid + st];
      red[TPB + tid] += red[TPB + tid + st];
      red[2 * TPB + tid] += red[2 * TPB + tid + st];
      red[3 * TPB + tid] += red[3 * TPB + tid + st];
    }
    __syncthreads();
  }
  if (tid == 0) {
    float* gp = gnpart + ((size_t)b * NBX + blockIdx.x) * 4;
    gp[0] = red[0]; gp[1] = red[TPB];
    gp[2] = red[2 * TPB]; gp[3] = red[3 * TPB];
  }
}

// ---- K4: reduce fwd2 partials -> per-group stats (1 block per (b,g), parallel) ----
__global__ __launch_bounds__(TPB) void k_gn_stats2(const float* __restrict__ part,
                                                   float* __restrict__ stats) {
  const int bg = blockIdx.x, b = bg >> 4, g = bg & 15;
  const int tid = threadIdx.x;
  const int clo = g * 8, chi = clo + 8;
  float s = 0.f, ss = 0.f;
  for (int bx = tid; bx < NBX; bx += TPB) {
    int c0 = (bx * 64) / WF;
    int c1 = (bx * 64 + 63) / WF;
    const float* p = part + ((size_t)b * NBX + bx) * 4;
    if (c0 >= clo && c0 < chi) { s += p[0]; ss += p[1]; }
    if (c1 != c0 && c1 >= clo && c1 < chi) { s += p[2]; ss += p[3]; }
  }
  __shared__ float rs[TPB], rq[TPB];
  rs[tid] = s; rq[tid] = ss;
  __syncthreads();
  for (int st = TPB / 2; st > 0; st >>= 1) {
    if (tid < st) { rs[tid] += rs[tid + st]; rq[tid] += rq[tid + st]; }
    __syncthreads();
  }
  if (tid == 0) {
    const float inv = 1.f / (8.f * (float)HWF);
    float mean = rs[0] * inv;
    float var = rq[0] * inv - mean * mean;
    stats[bg * 2] = mean;
    stats[bg * 2 + 1] = rsqrtf(var + GN_EPS);
  }
}

// ------- K5: GN+ReLU + k-fold: Z+/- [b][u'][k=0..127] -------
__global__ __launch_bounds__(TPB) void k_gnfold(
    const us16* __restrict__ Yt, const float* __restrict__ stats,
    const float* __restrict__ gamma, const float* __restrict__ beta,
    us16* __restrict__ Zrp, us16* __restrict__ Zrm,
    us16* __restrict__ Zip, us16* __restrict__ Zim) {
  const int b = blockIdx.y;
  const int up = blockIdx.x * 8 + (threadIdx.x >> 5);   // 0..8255
  const int l32 = threadIdx.x & 31;
  const int c = up / WF;
  const int g1 = b * 16 + (c >> 3), g2 = g1 + 8;
  const float sc1 = gamma[c] * stats[g1 * 2 + 1];
  const float sh1 = beta[c] - stats[g1 * 2] * sc1;
  const float sc2 = gamma[64 + c] * stats[g2 * 2 + 1];
  const float sh2 = beta[64 + c] - stats[g2 * 2] * sc2;
  const us16* ybase = Yt + (size_t)b * 128 * SP;
  const us16* yr = ybase + (size_t)up * 256;
  const us16* yi = ybase + (size_t)(64 * WF + up) * 256;
  const int k0 = l32 * 4;
  uint2 ar = *(const uint2*)(yr + k0);
  uint2 mr = *(const uint2*)(yr + 252 - k0);
  uint2 ai = *(const uint2*)(yi + k0);
  uint2 mi = *(const uint2*)(yi + 252 - k0);
  us16 arv[4] = {(us16)ar.x, (us16)(ar.x >> 16), (us16)ar.y, (us16)(ar.y >> 16)};
  us16 mrv[4] = {(us16)mr.x, (us16)(mr.x >> 16), (us16)mr.y, (us16)(mr.y >> 16)};
  us16 aiv[4] = {(us16)ai.x, (us16)(ai.x >> 16), (us16)ai.y, (us16)(ai.y >> 16)};
  us16 miv[4] = {(us16)mi.x, (us16)(mi.x >> 16), (us16)mi.y, (us16)(mi.y >> 16)};
  us16 rp[4], rm[4], ip[4], im[4];
#pragma unroll
  for (int d = 0; d < 4; ++d) {
    float zr = fmaxf(bf2f(arv[d]) * sc1 + sh1, 0.f);
    float zi = fmaxf(bf2f(aiv[d]) * sc2 + sh2, 0.f);
    float pr = 0.f, pi = 0.f;
    if (k0 + d > 0) {
      pr = fmaxf(bf2f(mrv[3 - d]) * sc1 + sh1, 0.f);
      pi = fmaxf(bf2f(miv[3 - d]) * sc2 + sh2, 0.f);
    }
    rp[d] = f2bf(zr + pr); rm[d] = f2bf(zr - pr);
    ip[d] = f2bf(zi + pi); im[d] = f2bf(zi - pi);
  }
  const size_t zo = ((size_t)b * UZ + up) * 128 + k0;
  uint2 o1; o1.x = (unsigned)rp[0] | ((unsigned)rp[1] << 16);
  o1.y = (unsigned)rp[2] | ((unsigned)rp[3] << 16);
  *(uint2*)(Zrp + zo) = o1;
  uint2 o2; o2.x = (unsigned)rm[0] | ((unsigned)rm[1] << 16);
  o2.y = (unsigned)rm[2] | ((unsigned)rm[3] << 16);
  *(uint2*)(Zrm + zo) = o2;
  uint2 o3; o3.x = (unsigned)ip[0] | ((unsigned)ip[1] << 16);
  o3.y = (unsigned)ip[2] | ((unsigned)ip[3] << 16);
  *(uint2*)(Zip + zo) = o3;
  uint2 o4; o4.x = (unsigned)im[0] | ((unsigned)im[1] << 16);
  o4.y = (unsigned)im[2] | ((unsigned)im[3] << 16);
  *(uint2*)(Zim + zo) = o4;
}

// ------- K6: inverse H-DFT, K folded to 128 -> Hr/Hi bf16 [bc*128+m][160] -------
__global__ __launch_bounds__(TPB) void k_dfth_inv_mfma(
    const us16* __restrict__ Zrp, const us16* __restrict__ Zrm,
    const us16* __restrict__ Zip, const us16* __restrict__ Zim,
    const us16* __restrict__ CbA, const us16* __restrict__ SbA,
    us16* __restrict__ Hr, us16* __restrict__ Hi, int hsel) {
  __shared__ __align__(16) us16 Ac[2][2][64][32];
  __shared__ __align__(16) us16 As[2][2][64][32];
  __shared__ __align__(16) us16 Brp[2][64][32];
  __shared__ __align__(16) us16 Brm[2][64][32];
  __shared__ __align__(16) us16 Bip[2][64][32];
  __shared__ __align__(16) us16 Bim[2][64][32];
  const int tid = threadIdx.x, w = tid >> 6, lane = tid & 63;
  const int b = blockIdx.z;
  const int u0 = blockIdx.x * 64;
  const int rsel = lane >> 2;
  const int csw = (lane & 3) ^ ((lane >> 3) & 3);
  const us16* gAc = CbA + (((size_t)hsel + 16 * w + rsel) << 8) + csw * 8;
  const us16* gAs = SbA + (((size_t)hsel + 16 * w + rsel) << 8) + csw * 8;
  const size_t zoff = ((size_t)b * UZ + u0 + 16 * w + rsel) * 128 + csw * 8;
  const us16* gZrp = Zrp + zoff;
  const us16* gZrm = Zrm + zoff;
  const us16* gZip = Zip + zoff;
  const us16* gZim = Zim + zoff;
  f32x4 accr[2][4] = {}, acci[2][4] = {};
  const int fr = lane & 15;
  const int kb = 8 * ((lane >> 4) ^ ((lane >> 1) & 3));
#define STAGE_K6(pp, k0) do { \
    gload16(gAc + (k0), &Ac[pp][0][16 * w][0]); \
    gload16(gAc + (1 << 14) + (k0), &Ac[pp][1][16 * w][0]); \
    gload16(gAs + (k0), &As[pp][0][16 * w][0]); \
    gload16(gAs + (1 << 14) + (k0), &As[pp][1][16 * w][0]); \
    gload16(gZrp + (k0), &Brp[pp][16 * w][0]); \
    gload16(gZrm + (k0), &Brm[pp][16 * w][0]); \
    gload16(gZip + (k0), &Bip[pp][16 * w][0]); \
    gload16(gZim + (k0), &Bim[pp][16 * w][0]); } while (0)
  STAGE_K6(0, 0);
  int pp = 0;
  for (int k0 = 0; k0 < 128; k0 += 32) {
    if (k0 + 32 < 128) { STAGE_K6(pp ^ 1, k0 + 32); WAITVM(8); }
    else WAITVM(0);
    BAR_ACQ();
    bf16x8 aC[2], aS[2], aSn[2];
#pragma unroll
    for (int mt = 0; mt < 2; ++mt) {
      aC[mt] = *(const bf16x8*)&Ac[pp][mt][16 * w + fr][kb];
      aS[mt] = *(const bf16x8*)&As[pp][mt][16 * w + fr][kb];
      uint4 su = *(const uint4*)&aS[mt];
      su.x ^= 0x80008000u; su.y ^= 0x80008000u; su.z ^= 0x80008000u; su.w ^= 0x80008000u;
      aSn[mt] = *(const bf16x8*)&su;
    }
#pragma unroll
    for (int t = 0; t < 4; ++t) {
      bf16x8 bRp = *(const bf16x8*)&Brp[pp][16 * t + fr][kb];
      bf16x8 bRm = *(const bf16x8*)&Brm[pp][16 * t + fr][kb];
      bf16x8 bIp = *(const bf16x8*)&Bip[pp][16 * t + fr][kb];
      bf16x8 bIm = *(const bf16x8*)&Bim[pp][16 * t + fr][kb];
#pragma unroll
      for (int mt = 0; mt < 2; ++mt) {
        accr[mt][t] = MFMA(aC[mt], bRp, accr[mt][t], 0, 0, 0);
        accr[mt][t] = MFMA(aSn[mt], bIm, accr[mt][t], 0, 0, 0);
        acci[mt][t] = MFMA(aC[mt], bIp, acci[mt][t], 0, 0, 0);
        acci[mt][t] = MFMA(aS[mt], bRm, acci[mt][t], 0, 0, 0);
      }
    }
    BAR_REL();
    pp ^= 1;
  }
  const float inv = 1.f / 255.f;
#pragma unroll
  for (int t = 0; t < 4; ++t) {
    int u = u0 + 16 * t + fr;
    int c = u / WF, n = u - c * WF;
#pragma unroll
    for (int mt = 0; mt < 2; ++mt) {
#pragma unroll
      for (int j = 0; j < 4; ++j) {
        int m = mt * 64 + 16 * w + 4 * (lane >> 4) + j;
        size_t idx = (((size_t)(b * 64 + c)) * 128 + m) * KH + n;
        Hr[idx] = f2bf(accr[mt][t][j] * inv);
        Hi[idx] = f2bf(acci[mt][t][j] * inv);
      }
    }
  }
}

// ------- K7: inverse W-DFT, W-symmetric (w=0..127 -> cols w and 256-w) -------
__global__ __launch_bounds__(TPB) void k_dftw_inv_mfma(
    const us16* __restrict__ Hr, const us16* __restrict__ Hi,
    const us16* __restrict__ Tci, const us16* __restrict__ Tsi,
    float* __restrict__ out, int roff, int b0) {
  __shared__ __align__(16) us16 Ar[2][64][32];
  __shared__ __align__(16) us16 Ai[2][64][32];
  __shared__ __align__(16) us16 Bc[2][64][32];
  __shared__ __align__(16) us16 Bs[2][64][32];
  const int tid = threadIdx.x, w = tid >> 6, lane = tid & 63;
  const int w0 = blockIdx.x * 64, mf0 = blockIdx.y * 64;
  const int rsel = lane >> 2;
  const int csw = (lane & 3) ^ ((lane >> 3) & 3);
  const us16* gAr = Hr + (size_t)(mf0 + 16 * w + rsel) * KH + csw * 8;
  const us16* gAi = Hi + (size_t)(mf0 + 16 * w + rsel) * KH + csw * 8;
  const us16* gBc = Tci + (size_t)(w0 + 16 * w + rsel) * KH + csw * 8;
  const us16* gBs = Tsi + (size_t)(w0 + 16 * w + rsel) * KH + csw * 8;
  f32x4 accU[4] = {}, accV[4] = {};
  const int fr = lane & 15;
  const int kb = 8 * ((lane >> 4) ^ ((lane >> 1) & 3));
#define STAGE_K7(pp, k0) do { \
    gload16(gAr + (k0), &Ar[pp][16 * w][0]); \
    gload16(gAi + (k0), &Ai[pp][16 * w][0]); \
    gload16(gBc + (k0), &Bc[pp][16 * w][0]); \
    gload16(gBs + (k0), &Bs[pp][16 * w][0]); } while (0)
  STAGE_K7(0, 0);
  int pp = 0;
  for (int k0 = 0; k0 < KH; k0 += 32) {
    if (k0 + 32 < KH) { STAGE_K7(pp ^ 1, k0 + 32); WAITVM(4); }
    else WAITVM(0);
    BAR_ACQ();
    bf16x8 aR = *(const bf16x8*)&Ar[pp][16 * w + fr][kb];
    bf16x8 aI = *(const bf16x8*)&Ai[pp][16 * w + fr][kb];
    uint4 su = *(const uint4*)&aI;
    su.x ^= 0x80008000u; su.y ^= 0x80008000u; su.z ^= 0x80008000u; su.w ^= 0x80008000u;
    bf16x8 aIn = *(const bf16x8*)&su;
#pragma unroll
    for (int t = 0; t < 4; ++t) {
      bf16x8 bC = *(const bf16x8*)&Bc[pp][16 * t + fr][kb];
      bf16x8 bS = *(const bf16x8*)&Bs[pp][16 * t + fr][kb];
      accU[t] = MFMA(aR, bC, accU[t], 0, 0, 0);
      accV[t] = MFMA(aIn, bS, accV[t], 0, 0, 0);
    }
    BAR_REL();
    pp ^= 1;
  }
#pragma unroll
  for (int t = 0; t < 4; ++t) {
    int wv = w0 + 16 * t + fr;                 // 0..127
#pragma unroll
    for (int j = 0; j < 4; ++j) {
      int mf = mf0 + 16 * w + 4 * (lane >> 4) + j;
      int bcl = mf >> 7, mrow = mf & 127;
      int bb = b0 + (bcl >> 6), cc = bcl & 63;
      size_t obase = (((size_t)bb * CH + cc) * HIN + roff + mrow) * WIN;
      float U = accU[t][j], V = accV[t][j];
      out[obase + wv] = U + V;
      if (wv > 0) out[obase + 256 - wv] = U - V;
    }
  }
}

// ------- K8: missing column w=128 (sin==0): alternating sum of Hr -------
__global__ __launch_bounds__(TPB) void k_w128(const us16* __restrict__ Hr,
                                              float* __restrict__ out,
                                              int roff, int b0) {
  const int mf = blockIdx.x * TPB + threadIdx.x;
  const us16* hr = Hr + (size_t)mf * KH;
  float s = bf2f(hr[0]) + bf2f(hr[128]);
  for (int k = 1; k < 128; k += 2)
    s += -2.f * bf2f(hr[k]) + 2.f * bf2f(hr[k + 1]);
  s -= 2.f * bf2f(hr[128]);
  s *= (1.f / 256.f);
  int bcl = mf >> 7, mrow = mf & 127;
  int bb = b0 + (bcl >> 6), cc = bcl & 63;
  out[(((size_t)bb * CH + cc) * HIN + roff + mrow) * WIN + 128] = s;
}

// ---------------- host ----------------
extern "C" void kernel_launch(void* const* d_in, const int* in_sizes, int n_in,
                              void* d_out, int out_size, void* d_ws, size_t ws_size,
                              hipStream_t stream) {
  const float* x        = (const float*)d_in[0];
  const float* conv_w   = (const float*)d_in[1];
  const float* conv_b   = (const float*)d_in[2];
  const float* gn_gamma = (const float*)d_in[3];
  const float* gn_beta  = (const float*)d_in[4];
  float* out = (float*)d_out;

  // u16 units
  const size_t uCbA = 2 * 65536;
  const size_t uTcb = 128 * 256;
  const size_t uTci = (size_t)256 * KH;
  const size_t uW   = 128 * 128;
  const size_t fixed_u16 = 2 * uCbA + 2 * uTcb + 2 * uTci + 2 * uW;
  const size_t uXB = (size_t)CH * HIN * WIN;      // 4194304
  const size_t uF  = (size_t)CH * SP;             // 2113536
  const size_t uPQ = (size_t)128 * SP;            // 4227072
  const size_t uYT = (size_t)128 * SP;            // 4227072 (aliases xb/Frt)
  const size_t uH  = (size_t)CH * 128 * KH;       // 1310720
  const size_t uZ1 = (size_t)UZ * 128;            // 1056768 per Z array
  const size_t per_u16 = uXB + 2 * uF + 2 * uPQ + 4 * uZ1;  // 21102592
  const size_t nPart = 4 * 4 * NBX + 128;

  int nb = 0;
  for (int cand = 4; cand >= 1; cand >>= 1) {
    size_t need = fixed_u16 * 2 + nPart * 4 + (size_t)cand * per_u16 * 2 + 256;
    if (need <= ws_size) { nb = cand; break; }
  }
  if (nb == 0) {
    k_zero<<<dim3((out_size + TPB - 1) / TPB), dim3(TPB), 0, stream>>>(out, out_size);
    return;
  }

  us16* CbA = (us16*)d_ws;
  us16* SbA = CbA + uCbA;
  us16* Tcb = SbA + uCbA;
  us16* Tsb = Tcb + uTcb;
  us16* Tci = Tsb + uTcb;
  us16* Tsi = Tci + uTci;
  us16* Wpb = Tsi + uTci;
  us16* Wqb = Wpb + uW;
  float* part  = (float*)(Wqb + uW);
  float* stats = part + 4 * NBX * 4;
  us16* xb  = (us16*)(stats + 128);
  us16* Frt = xb + (size_t)nb * uXB;
  us16* Fit = Frt + (size_t)nb * uF;
  us16* P   = Fit + (size_t)nb * uF;
  us16* Q   = P + (size_t)nb * uPQ;
  us16* Zrp = Q + (size_t)nb * uPQ;
  us16* Zrm = Zrp + (size_t)nb * uZ1;
  us16* Zip = Zrm + (size_t)nb * uZ1;
  us16* Zim = Zip + (size_t)nb * uZ1;
  // aliases into [xb | Frt | Fit] (dead after k_mix): Yt then Hr/Hi
  us16* Yt  = xb;
  us16* Hr  = xb + (size_t)nb * uYT;
  us16* Hi  = Hr + (size_t)nb * uH;

  k_tables<<<dim3(512), dim3(TPB), 0, stream>>>(CbA, SbA, Tcb, Tsb, Tci, Tsi,
                                                Wpb, Wqb, conv_w);

  for (int b0 = 0; b0 < B_ALL; b0 += nb) {
    k_xcast2<<<dim3(nb * 4096), dim3(TPB), 0, stream>>>(
        x + (size_t)b0 * CH * HIN * WIN, xb, Frt, Fit);
    k_dftw_fwd_mfma<<<dim3(nb * 256), dim3(TPB), 0, stream>>>(
        xb, Tcb, Tsb, Frt, Fit);
    k_mix<<<dim3(SP / 64, 1, nb), dim3(TPB), 0, stream>>>(
        Frt, Fit, Wpb, Wqb, P, Q);
    for (int fu = 0; fu < 2; ++fu) {
      const int hsel = fu ? 127 : 0;
      const int roff = fu ? 128 : 0;
      k_dfth_fwd2<<<dim3(NBX, 1, nb), dim3(TPB), 0, stream>>>(
          P, Q, CbA, SbA, conv_b, Yt, part, fu);
      k_gn_stats2<<<dim3(nb * 16), dim3(TPB), 0, stream>>>(part, stats);
      k_gnfold<<<dim3(UZ / 8, nb), dim3(TPB), 0, stream>>>(
          Yt, stats, gn_gamma, gn_beta, Zrp, Zrm, Zip, Zim);
      k_dfth_inv_mfma<<<dim3(UZ / 64, 1, nb), dim3(TPB), 0, stream>>>(
          Zrp, Zrm, Zip, Zim, CbA, SbA, Hr, Hi, hsel);
      k_dftw_inv_mfma<<<dim3(2, nb * 128), dim3(TPB), 0, stream>>>(
          Hr, Hi, Tci, Tsi, out, roff, b0);
      k_w128<<<dim3(nb * 32), dim3(TPB), 0, stream>>>(Hr, out, roff, b0);
    }
  }
}

// Round 21
// 224.362 us; speedup vs baseline: 1.1594x; 1.1072x over previous
//
#include <hip/hip_runtime.h>
#include <math.h>

#define TPB 256

typedef unsigned short us16;
typedef __bf16 bf16x8 __attribute__((ext_vector_type(8)));
typedef float f32x4 __attribute__((ext_vector_type(4)));

static const int B_ALL = 4;
static const int CH   = 64;
static const int HIN  = 256, WIN = 256;
static const int HH   = 255;
static const int WF   = 129;          // valid n per channel
static const int HWF  = HH * WF;      // 32895 valid GN count per channel
static const int SP   = WF * 256;     // 33024 packed spatial per channel
static const int KH   = 160;          // padded K for inverse W-DFT
static const int UZ   = 64 * WF;      // 8256 packed (c,n) rows per batch (inv side)
static const int NBX  = 258;          // fwd2 blocks per batch per fu
#define GN_EPS 1e-5f

__device__ __forceinline__ us16 f2bf(float f) {
  union { float f; unsigned u; } v; v.f = f;
  unsigned r = v.u + 0x7FFFu + ((v.u >> 16) & 1u);
  return (us16)(r >> 16);
}
__device__ __forceinline__ float bf2f(us16 v) {
  union { unsigned u; float f; } t; t.u = ((unsigned)v) << 16; return t.f;
}
__device__ __forceinline__ void gload16(const void* g, void* l) {
  __builtin_amdgcn_global_load_lds(
      (const __attribute__((address_space(1))) unsigned int*)g,
      (__attribute__((address_space(3))) unsigned int*)l, 16, 0, 0);
}
#define MFMA __builtin_amdgcn_mfma_f32_16x16x32_bf16
#define WAITVM(N) asm volatile("s_waitcnt vmcnt(" #N ")" ::: "memory")
#define BAR_ACQ() do { \
    __builtin_amdgcn_s_barrier(); \
    asm volatile("" ::: "memory"); \
    __builtin_amdgcn_sched_barrier(0); } while (0)
#define BAR_REL() do { \
    asm volatile("" ::: "memory"); \
    __builtin_amdgcn_s_barrier(); } while (0)

// ---------------- fallback ----------------
__global__ __launch_bounds__(TPB) void k_zero(float* __restrict__ out, int n) {
  int i = blockIdx.x * TPB + threadIdx.x;
  if (i < n) out[i] = 0.f;
}

// ---- cast x f32->bf16 (one wave per row) + analytic Nyquist bin n=128 ----
__global__ __launch_bounds__(TPB) void k_xcast2(const float* __restrict__ x,
                                                us16* __restrict__ xb,
                                                us16* __restrict__ Frt,
                                                us16* __restrict__ Fit) {
  const int row = blockIdx.x * 4 + (threadIdx.x >> 6);
  const int lane = threadIdx.x & 63;
  float4 v = ((const float4*)(x + (size_t)row * 256))[lane];
  ushort4 o;
  o.x = f2bf(v.x); o.y = f2bf(v.y); o.z = f2bf(v.z); o.w = f2bf(v.w);
  ((ushort4*)(xb + (size_t)row * 256))[lane] = o;
  float alt = v.x - v.y + v.z - v.w;
  for (int off = 32; off; off >>= 1) alt += __shfl_down(alt, off);
  if (lane == 0) {
    int bc = row >> 8, h = row & 255;
    size_t idx = ((size_t)bc * WF + 128) * 256 + h;
    Frt[idx] = f2bf(alt);
    Fit[idx] = 0;
  }
}

// ---------------- bf16 tables ----------------
__global__ __launch_bounds__(TPB) void k_tables(
    us16* __restrict__ CbA, us16* __restrict__ SbA,
    us16* __restrict__ Tcb, us16* __restrict__ Tsb,
    us16* __restrict__ Tci, us16* __restrict__ Tsi,
    us16* __restrict__ Wpb, us16* __restrict__ Wqb,
    const float* __restrict__ conv_w) {
  int i = blockIdx.x * TPB + threadIdx.x;
  const double PI2 = 6.283185307179586476925286766559;
  if (i < 2 * 65536) {                      // H-DFT [fu][r][k], k-shift absorbed
    int fu = i >> 16, r = (i >> 8) & 255, k = i & 255;
    float cv = 0.f, sv = 0.f;
    int kk = k - fu;
    if (r < 255 && kk >= 0 && kk < 255) {
      double ang = PI2 * (double)((r * kk) % 255) / 255.0;
      cv = (float)cos(ang); sv = (float)sin(ang);
    }
    CbA[i] = f2bf(cv); SbA[i] = f2bf(sv);
  }
  if (i < 128 * 256) {                      // W-DFT fwd transposed [n<128][w]
    int n = i >> 8, w = i & 255;
    double ang = PI2 * (double)((n * w) & 255) / 256.0;
    Tcb[i] = f2bf((float)cos(ang));
    Tsb[i] = f2bf((float)sin(ang));
  }
  if (i < 256 * KH) {                       // W-DFT inv [w][k], Hermitian coef
    int w = i / KH, k = i - w * KH;
    float cv = 0.f, sv = 0.f;
    if (k < WF) {
      double coef = (k == 0 || k == 128) ? 1.0 : 2.0;
      double ang = PI2 * (double)((k * w) & 255) / 256.0;
      cv = (float)(coef * cos(ang) / 256.0);
      sv = (float)(coef * sin(ang) / 256.0);
    }
    Tci[i] = f2bf(cv); Tsi[i] = f2bf(sv);
  }
  if (i < 128 * 128) {                      // mix weights
    int o = i >> 7, c = i & 127;
    Wpb[i] = f2bf(conv_w[i]);
    float q = (c < 64) ? -conv_w[o * 128 + 64 + c] : conv_w[o * 128 + c - 64];
    Wqb[i] = f2bf(q);
  }
}

// ------- K1: forward W-DFT, BOTH n-halves per block (B staged once) -------
__global__ __launch_bounds__(TPB) void k_dftw_fwd_mfma(
    const us16* __restrict__ xb, const us16* __restrict__ Tcb,
    const us16* __restrict__ Tsb, us16* __restrict__ Frt, us16* __restrict__ Fit) {
  __shared__ __align__(16) us16 Ac[2][2][64][32];   // [pp][half]
  __shared__ __align__(16) us16 As[2][2][64][32];
  __shared__ __align__(16) us16 Bx[2][64][32];
  const int tid = threadIdx.x, w = tid >> 6, lane = tid & 63;
  const int hb = blockIdx.x;
  const int rsel = lane >> 2;
  const int csw = (lane & 3) ^ ((lane >> 3) & 3);
  const us16* gAc = Tcb + (size_t)(16 * w + rsel) * 256 + csw * 8;
  const us16* gAs = Tsb + (size_t)(16 * w + rsel) * 256 + csw * 8;
  const us16* gB  = xb + ((size_t)hb * 64 + 16 * w + rsel) * 256 + csw * 8;
  f32x4 accr[2][4] = {}, acci[2][4] = {};
  const int fr = lane & 15;
  const int kb = 8 * ((lane >> 4) ^ ((lane >> 1) & 3));
#define STAGE_K1(pp, k0) do { \
    gload16(gAc + (k0), &Ac[pp][0][16 * w][0]); \
    gload16(gAc + 64 * 256 + (k0), &Ac[pp][1][16 * w][0]); \
    gload16(gAs + (k0), &As[pp][0][16 * w][0]); \
    gload16(gAs + 64 * 256 + (k0), &As[pp][1][16 * w][0]); \
    gload16(gB + (k0), &Bx[pp][16 * w][0]); } while (0)
  STAGE_K1(0, 0);
  int pp = 0;
  for (int k0 = 0; k0 < 256; k0 += 32) {
    if (k0 + 32 < 256) { STAGE_K1(pp ^ 1, k0 + 32); WAITVM(5); }
    else WAITVM(0);
    BAR_ACQ();
    bf16x8 aC[2], aSn[2];
#pragma unroll
    for (int g = 0; g < 2; ++g) {
      aC[g] = *(const bf16x8*)&Ac[pp][g][16 * w + fr][kb];
      bf16x8 aS = *(const bf16x8*)&As[pp][g][16 * w + fr][kb];
      uint4 su = *(const uint4*)&aS;
      su.x ^= 0x80008000u; su.y ^= 0x80008000u; su.z ^= 0x80008000u; su.w ^= 0x80008000u;
      aSn[g] = *(const bf16x8*)&su;
    }
#pragma unroll
    for (int t = 0; t < 4; ++t) {
      bf16x8 b = *(const bf16x8*)&Bx[pp][16 * t + fr][kb];
#pragma unroll
      for (int g = 0; g < 2; ++g) {
        accr[g][t] = MFMA(aC[g], b, accr[g][t], 0, 0, 0);
        acci[g][t] = MFMA(aSn[g], b, acci[g][t], 0, 0, 0);
      }
    }
    BAR_REL();
    pp ^= 1;
  }
  const int bc = hb >> 2, hl = (hb & 3) * 64;
#pragma unroll
  for (int g = 0; g < 2; ++g) {
#pragma unroll
    for (int t = 0; t < 4; ++t) {
      int h = hl + 16 * t + fr;
#pragma unroll
      for (int j = 0; j < 4; ++j) {
        int n = g * 64 + 16 * w + 4 * (lane >> 4) + j;
        size_t idx = ((size_t)bc * WF + n) * 256 + h;
        Frt[idx] = f2bf(accr[g][t][j]);
        Fit[idx] = f2bf(acci[g][t][j]);
      }
    }
  }
}

// ------- K2: channel-mix, BOTH o-tiles per block (B staged once) -------
__global__ __launch_bounds__(TPB) void k_mix(
    const us16* __restrict__ Frt, const us16* __restrict__ Fit,
    const us16* __restrict__ Wpb, const us16* __restrict__ Wqb,
    us16* __restrict__ P, us16* __restrict__ Q) {
  __shared__ __align__(16) us16 Ap[2][64][32];
  __shared__ __align__(16) us16 Aq[2][64][32];
  __shared__ __align__(8)  us16 Bs[64][36];
  const int tid = threadIdx.x, w = tid >> 6, lane = tid & 63;
  const int sp0 = blockIdx.x * 64, b = blockIdx.z;
  const int rsel = lane >> 2;
  const int csw = (lane & 3) ^ ((lane >> 3) & 3);
  const us16* gAp0 = Wpb + (size_t)(16 * w + rsel) * 128 + csw * 8;
  const us16* gAq0 = Wqb + (size_t)(16 * w + rsel) * 128 + csw * 8;
  f32x4 accp[2][4] = {}, accq[2][4] = {};
  const int fr = lane & 15;
  const int kbA = 8 * ((lane >> 4) ^ ((lane >> 1) & 3));
  const int kbB = 8 * (lane >> 4);
  for (int c0 = 0; c0 < 128; c0 += 32) {
    gload16(gAp0 + c0, &Ap[0][16 * w][0]);
    gload16(gAp0 + 64 * 128 + c0, &Ap[1][16 * w][0]);
    gload16(gAq0 + c0, &Aq[0][16 * w][0]);
    gload16(gAq0 + 64 * 128 + c0, &Aq[1][16 * w][0]);
    for (int f = tid; f < 1024; f += TPB) {
      int cl = f >> 5, spp = f & 31;
      int c = c0 + cl;
      const us16* src = (c < 64) ? Frt : Fit;
      size_t addr = (size_t)(b * 64 + (c & 63)) * SP + sp0 + 2 * spp;
      unsigned v = *(const unsigned*)(src + addr);
      Bs[2 * spp][cl] = (us16)v;
      Bs[2 * spp + 1][cl] = (us16)(v >> 16);
    }
    __syncthreads();
    bf16x8 aP0 = *(const bf16x8*)&Ap[0][16 * w + fr][kbA];
    bf16x8 aP1 = *(const bf16x8*)&Ap[1][16 * w + fr][kbA];
    bf16x8 aQ0 = *(const bf16x8*)&Aq[0][16 * w + fr][kbA];
    bf16x8 aQ1 = *(const bf16x8*)&Aq[1][16 * w + fr][kbA];
#pragma unroll
    for (int t = 0; t < 4; ++t) {
      uint2 lo = *(const uint2*)&Bs[16 * t + fr][kbB];
      uint2 hi = *(const uint2*)&Bs[16 * t + fr][kbB + 4];
      uint4 qq; qq.x = lo.x; qq.y = lo.y; qq.z = hi.x; qq.w = hi.y;
      bf16x8 bb = *(const bf16x8*)&qq;
      accp[0][t] = MFMA(aP0, bb, accp[0][t], 0, 0, 0);
      accp[1][t] = MFMA(aP1, bb, accp[1][t], 0, 0, 0);
      accq[0][t] = MFMA(aQ0, bb, accq[0][t], 0, 0, 0);
      accq[1][t] = MFMA(aQ1, bb, accq[1][t], 0, 0, 0);
    }
    __syncthreads();
  }
#pragma unroll
  for (int t = 0; t < 4; ++t) {
    int sp = sp0 + 16 * t + fr;
#pragma unroll
    for (int ot = 0; ot < 2; ++ot)
#pragma unroll
      for (int j = 0; j < 4; ++j) {
        int o = ot * 64 + 16 * w + 4 * (lane >> 4) + j;
        size_t idx = (size_t)(b * 128 + o) * SP + sp;
        P[idx] = f2bf(accp[ot][t][j]);
        Q[idx] = f2bf(accq[ot][t][j]);
      }
  }
}

// ------- K3: H-DFT fwd, fu = blockIdx.y; M-symmetric + fused GN partial stats -------
__global__ __launch_bounds__(TPB) void k_dfth_fwd2(
    const us16* __restrict__ P, const us16* __restrict__ Q,
    const us16* __restrict__ CbA, const us16* __restrict__ SbA,
    const float* __restrict__ bias, us16* __restrict__ Yt0,
    us16* __restrict__ Yt1, float* __restrict__ gnpart) {
  __shared__ __align__(16) us16 Ac[2][2][64][32];
  __shared__ __align__(16) us16 As[2][2][64][32];
  __shared__ __align__(16) us16 Bp[2][64][32];
  __shared__ __align__(16) us16 Bq[2][64][32];
  __shared__ float red[4 * TPB];
  const int tid = threadIdx.x, w = tid >> 6, lane = tid & 63;
  const int fu = blockIdx.y;
  const int b = blockIdx.z;
  const int u0 = blockIdx.x * 64;
  const int rsel = lane >> 2;
  const int csw = (lane & 3) ^ ((lane >> 3) & 3);
  const us16* gAc = CbA + (((size_t)fu * 256 + 16 * w + rsel) << 8) + csw * 8;
  const us16* gAs = SbA + (((size_t)fu * 256 + 16 * w + rsel) << 8) + csw * 8;
  const us16* gBp = P + (size_t)b * 128 * SP + (size_t)(u0 + 16 * w + rsel) * 256 + csw * 8;
  const us16* gBq = Q + (size_t)b * 128 * SP + (size_t)(u0 + 16 * w + rsel) * 256 + csw * 8;
  f32x4 cp[2][4] = {}, sq[2][4] = {};
  const int fr = lane & 15;
  const int kb = 8 * ((lane >> 4) ^ ((lane >> 1) & 3));
#define STAGE_K3(pp, k0) do { \
    _Pragma("unroll") \
    for (int mt = 0; mt < 2; ++mt) { \
      gload16(gAc + (mt << 14) + (k0), &Ac[pp][mt][16 * w][0]); \
      gload16(gAs + (mt << 14) + (k0), &As[pp][mt][16 * w][0]); } \
    gload16(gBp + (k0), &Bp[pp][16 * w][0]); \
    gload16(gBq + (k0), &Bq[pp][16 * w][0]); } while (0)
  STAGE_K3(0, 0);
  int pp = 0;
  for (int k0 = 0; k0 < 256; k0 += 32) {
    if (k0 + 32 < 256) { STAGE_K3(pp ^ 1, k0 + 32); WAITVM(6); }
    else WAITVM(0);
    BAR_ACQ();
    bf16x8 aC[2], aS[2];
#pragma unroll
    for (int mt = 0; mt < 2; ++mt) {
      aC[mt] = *(const bf16x8*)&Ac[pp][mt][16 * w + fr][kb];
      aS[mt] = *(const bf16x8*)&As[pp][mt][16 * w + fr][kb];
    }
#pragma unroll
    for (int t = 0; t < 4; ++t) {
      bf16x8 bP = *(const bf16x8*)&Bp[pp][16 * t + fr][kb];
      bf16x8 bQ = *(const bf16x8*)&Bq[pp][16 * t + fr][kb];
#pragma unroll
      for (int mt = 0; mt < 2; ++mt) {
        cp[mt][t] = MFMA(aC[mt], bP, cp[mt][t], 0, 0, 0);
        sq[mt][t] = MFMA(aS[mt], bQ, sq[mt][t], 0, 0, 0);
      }
    }
    BAR_REL();
    pp ^= 1;
  }
  us16* yb = (fu ? Yt1 : Yt0) + (size_t)b * 128 * SP;
  const int mb_ = 16 * w + 4 * (lane >> 4);
  const int ub = (u0 / WF + 1) * WF;           // first u of bucket-1 channel
  float s0 = 0.f, q0 = 0.f, s1 = 0.f, q1 = 0.f;
#pragma unroll
  for (int t = 0; t < 4; ++t) {
    int u = u0 + 16 * t + fr;
    float bo = bias[u / WF];
    float ts = 0.f, tq = 0.f;
#pragma unroll
    for (int mt = 0; mt < 2; ++mt) {
      int base = mt * 64 + mb_;                // r = base + j, 0..127
      float y[4], z[4];
#pragma unroll
      for (int j = 0; j < 4; ++j) {
        y[j] = cp[mt][t][j] + sq[mt][t][j] + bo; // row r
        z[j] = cp[mt][t][j] - sq[mt][t][j] + bo; // row 255-r
        ts += y[j]; tq += y[j] * y[j];
        if (base + j) { ts += z[j]; tq += z[j] * z[j]; }  // skip m==255 pad
      }
      uint2 pk;
      pk.x = (unsigned)f2bf(y[0]) | ((unsigned)f2bf(y[1]) << 16);
      pk.y = (unsigned)f2bf(y[2]) | ((unsigned)f2bf(y[3]) << 16);
      *(uint2*)(yb + (size_t)u * 256 + base) = pk;
      uint2 pk2;                               // reversed: m' = 252-base .. 255-base
      pk2.x = (unsigned)f2bf(z[3]) | ((unsigned)f2bf(z[2]) << 16);
      pk2.y = (unsigned)f2bf(z[1]) | ((unsigned)f2bf(z[0]) << 16);
      *(uint2*)(yb + (size_t)u * 256 + 252 - base) = pk2;
    }
    if (u >= ub) { s1 += ts; q1 += tq; } else { s0 += ts; q0 += tq; }
  }
  __syncthreads();
  red[tid] = s0; red[TPB + tid] = q0;
  red[2 * TPB + tid] = s1; red[3 * TPB + tid] = q1;
  __syncthreads();
  for (int st = TPB / 2; st > 0; st >>= 1) {
    if (tid < st) {
      red[tid] += red[tid + st];
      red[TPB + tid] += red[TPB + tid + st];
      red[2 * TPB + tid] += red[2 * TPB + tid + st];
      red[3 * TPB + tid] += red[3 * TPB + tid + st];
    }
    __syncthreads();
  }
  if (tid == 0) {
    float* gp = gnpart + ((((size_t)fu * gridDim.z) + b) * NBX + blockIdx.x) * 4;
    gp[0] = red[0]; gp[1] = red[TPB];
    gp[2] = red[2 * TPB]; gp[3] = red[3 * TPB];
  }
}

// ---- K4: reduce fwd2 partials -> per-group stats (fu = blockIdx.y) ----
__global__ __launch_bounds__(TPB) void k_gn_stats2(const float* __restrict__ part,
                                                   float* __restrict__ stats) {
  const int bg = blockIdx.x, b = bg >> 4, g = bg & 15;
  const int fu = blockIdx.y;
  const int nbv = gridDim.x >> 4;
  const float* pbase = part + (size_t)fu * nbv * NBX * 4;
  const int tid = threadIdx.x;
  const int clo = g * 8, chi = clo + 8;
  float s = 0.f, ss = 0.f;
  for (int bx = tid; bx < NBX; bx += TPB) {
    int c0 = (bx * 64) / WF;
    int c1 = (bx * 64 + 63) / WF;
    const float* p = pbase + ((size_t)b * NBX + bx) * 4;
    if (c0 >= clo && c0 < chi) { s += p[0]; ss += p[1]; }
    if (c1 != c0 && c1 >= clo && c1 < chi) { s += p[2]; ss += p[3]; }
  }
  __shared__ float rs[TPB], rq[TPB];
  rs[tid] = s; rq[tid] = ss;
  __syncthreads();
  for (int st = TPB / 2; st > 0; st >>= 1) {
    if (tid < st) { rs[tid] += rs[tid + st]; rq[tid] += rq[tid + st]; }
    __syncthreads();
  }
  if (tid == 0) {
    const float inv = 1.f / (8.f * (float)HWF);
    float mean = rs[0] * inv;
    float var = rq[0] * inv - mean * mean;
    float* sb = stats + (size_t)fu * nbv * 32;
    sb[bg * 2] = mean;
    sb[bg * 2 + 1] = rsqrtf(var + GN_EPS);
  }
}

// ------- K5: GN+ReLU + k-fold (fu = blockIdx.z): Z+/- [fu][b][u'][k] -------
__global__ __launch_bounds__(TPB) void k_gnfold(
    const us16* __restrict__ Yt0, const us16* __restrict__ Yt1,
    const float* __restrict__ stats,
    const float* __restrict__ gamma, const float* __restrict__ beta,
    us16* __restrict__ Zrp, us16* __restrict__ Zrm,
    us16* __restrict__ Zip, us16* __restrict__ Zim) {
  const int b = blockIdx.y;
  const int fu = blockIdx.z;
  const int nbv = gridDim.y;
  const int up = blockIdx.x * 8 + (threadIdx.x >> 5);   // 0..8255
  const int l32 = threadIdx.x & 31;
  const int c = up / WF;
  const float* sb = stats + (size_t)fu * nbv * 32;
  const int g1 = b * 16 + (c >> 3), g2 = g1 + 8;
  const float sc1 = gamma[c] * sb[g1 * 2 + 1];
  const float sh1 = beta[c] - sb[g1 * 2] * sc1;
  const float sc2 = gamma[64 + c] * sb[g2 * 2 + 1];
  const float sh2 = beta[64 + c] - sb[g2 * 2] * sc2;
  const us16* ybase = (fu ? Yt1 : Yt0) + (size_t)b * 128 * SP;
  const us16* yr = ybase + (size_t)up * 256;
  const us16* yi = ybase + (size_t)(64 * WF + up) * 256;
  const int k0 = l32 * 4;
  uint2 ar = *(const uint2*)(yr + k0);
  uint2 mr = *(const uint2*)(yr + 252 - k0);
  uint2 ai = *(const uint2*)(yi + k0);
  uint2 mi = *(const uint2*)(yi + 252 - k0);
  us16 arv[4] = {(us16)ar.x, (us16)(ar.x >> 16), (us16)ar.y, (us16)(ar.y >> 16)};
  us16 mrv[4] = {(us16)mr.x, (us16)(mr.x >> 16), (us16)mr.y, (us16)(mr.y >> 16)};
  us16 aiv[4] = {(us16)ai.x, (us16)(ai.x >> 16), (us16)ai.y, (us16)(ai.y >> 16)};
  us16 miv[4] = {(us16)mi.x, (us16)(mi.x >> 16), (us16)mi.y, (us16)(mi.y >> 16)};
  us16 rp[4], rm[4], ip[4], im[4];
#pragma unroll
  for (int d = 0; d < 4; ++d) {
    float zr = fmaxf(bf2f(arv[d]) * sc1 + sh1, 0.f);
    float zi = fmaxf(bf2f(aiv[d]) * sc2 + sh2, 0.f);
    float pr = 0.f, pi = 0.f;
    if (k0 + d > 0) {
      pr = fmaxf(bf2f(mrv[3 - d]) * sc1 + sh1, 0.f);
      pi = fmaxf(bf2f(miv[3 - d]) * sc2 + sh2, 0.f);
    }
    rp[d] = f2bf(zr + pr); rm[d] = f2bf(zr - pr);
    ip[d] = f2bf(zi + pi); im[d] = f2bf(zi - pi);
  }
  const size_t zo = (((size_t)fu * nbv + b) * UZ + up) * 128 + k0;
  uint2 o1; o1.x = (unsigned)rp[0] | ((unsigned)rp[1] << 16);
  o1.y = (unsigned)rp[2] | ((unsigned)rp[3] << 16);
  *(uint2*)(Zrp + zo) = o1;
  uint2 o2; o2.x = (unsigned)rm[0] | ((unsigned)rm[1] << 16);
  o2.y = (unsigned)rm[2] | ((unsigned)rm[3] << 16);
  *(uint2*)(Zrm + zo) = o2;
  uint2 o3; o3.x = (unsigned)ip[0] | ((unsigned)ip[1] << 16);
  o3.y = (unsigned)ip[2] | ((unsigned)ip[3] << 16);
  *(uint2*)(Zip + zo) = o3;
  uint2 o4; o4.x = (unsigned)im[0] | ((unsigned)im[1] << 16);
  o4.y = (unsigned)im[2] | ((unsigned)im[3] << 16);
  *(uint2*)(Zim + zo) = o4;
}

// ------- K6: inverse H-DFT (fu = blockIdx.y), K folded to 128 -> H[fu] -------
__global__ __launch_bounds__(TPB) void k_dfth_inv_mfma(
    const us16* __restrict__ Zrp, const us16* __restrict__ Zrm,
    const us16* __restrict__ Zip, const us16* __restrict__ Zim,
    const us16* __restrict__ CbA, const us16* __restrict__ SbA,
    us16* __restrict__ Hr0, us16* __restrict__ Hi0,
    us16* __restrict__ Hr1, us16* __restrict__ Hi1) {
  __shared__ __align__(16) us16 Ac[2][2][64][32];
  __shared__ __align__(16) us16 As[2][2][64][32];
  __shared__ __align__(16) us16 Brp[2][64][32];
  __shared__ __align__(16) us16 Brm[2][64][32];
  __shared__ __align__(16) us16 Bip[2][64][32];
  __shared__ __align__(16) us16 Bim[2][64][32];
  const int tid = threadIdx.x, w = tid >> 6, lane = tid & 63;
  const int fu = blockIdx.y;
  const int b = blockIdx.z;
  const int nbv = gridDim.z;
  const int hsel = fu ? 127 : 0;
  const int u0 = blockIdx.x * 64;
  const int rsel = lane >> 2;
  const int csw = (lane & 3) ^ ((lane >> 3) & 3);
  const us16* gAc = CbA + (((size_t)hsel + 16 * w + rsel) << 8) + csw * 8;
  const us16* gAs = SbA + (((size_t)hsel + 16 * w + rsel) << 8) + csw * 8;
  const size_t zoff = (((size_t)fu * nbv + b) * UZ + u0 + 16 * w + rsel) * 128 + csw * 8;
  const us16* gZrp = Zrp + zoff;
  const us16* gZrm = Zrm + zoff;
  const us16* gZip = Zip + zoff;
  const us16* gZim = Zim + zoff;
  f32x4 accr[2][4] = {}, acci[2][4] = {};
  const int fr = lane & 15;
  const int kb = 8 * ((lane >> 4) ^ ((lane >> 1) & 3));
#define STAGE_K6(pp, k0) do { \
    gload16(gAc + (k0), &Ac[pp][0][16 * w][0]); \
    gload16(gAc + (1 << 14) + (k0), &Ac[pp][1][16 * w][0]); \
    gload16(gAs + (k0), &As[pp][0][16 * w][0]); \
    gload16(gAs + (1 << 14) + (k0), &As[pp][1][16 * w][0]); \
    gload16(gZrp + (k0), &Brp[pp][16 * w][0]); \
    gload16(gZrm + (k0), &Brm[pp][16 * w][0]); \
    gload16(gZip + (k0), &Bip[pp][16 * w][0]); \
    gload16(gZim + (k0), &Bim[pp][16 * w][0]); } while (0)
  STAGE_K6(0, 0);
  int pp = 0;
  for (int k0 = 0; k0 < 128; k0 += 32) {
    if (k0 + 32 < 128) { STAGE_K6(pp ^ 1, k0 + 32); WAITVM(8); }
    else WAITVM(0);
    BAR_ACQ();
    bf16x8 aC[2], aS[2], aSn[2];
#pragma unroll
    for (int mt = 0; mt < 2; ++mt) {
      aC[mt] = *(const bf16x8*)&Ac[pp][mt][16 * w + fr][kb];
      aS[mt] = *(const bf16x8*)&As[pp][mt][16 * w + fr][kb];
      uint4 su = *(const uint4*)&aS[mt];
      su.x ^= 0x80008000u; su.y ^= 0x80008000u; su.z ^= 0x80008000u; su.w ^= 0x80008000u;
      aSn[mt] = *(const bf16x8*)&su;
    }
#pragma unroll
    for (int t = 0; t < 4; ++t) {
      bf16x8 bRp = *(const bf16x8*)&Brp[pp][16 * t + fr][kb];
      bf16x8 bRm = *(const bf16x8*)&Brm[pp][16 * t + fr][kb];
      bf16x8 bIp = *(const bf16x8*)&Bip[pp][16 * t + fr][kb];
      bf16x8 bIm = *(const bf16x8*)&Bim[pp][16 * t + fr][kb];
#pragma unroll
      for (int mt = 0; mt < 2; ++mt) {
        accr[mt][t] = MFMA(aC[mt], bRp, accr[mt][t], 0, 0, 0);
        accr[mt][t] = MFMA(aSn[mt], bIm, accr[mt][t], 0, 0, 0);
        acci[mt][t] = MFMA(aC[mt], bIp, acci[mt][t], 0, 0, 0);
        acci[mt][t] = MFMA(aS[mt], bRm, acci[mt][t], 0, 0, 0);
      }
    }
    BAR_REL();
    pp ^= 1;
  }
  us16* Hr = fu ? Hr1 : Hr0;
  us16* Hi = fu ? Hi1 : Hi0;
  const float inv = 1.f / 255.f;
#pragma unroll
  for (int t = 0; t < 4; ++t) {
    int u = u0 + 16 * t + fr;
    int c = u / WF, n = u - c * WF;
#pragma unroll
    for (int mt = 0; mt < 2; ++mt) {
#pragma unroll
      for (int j = 0; j < 4; ++j) {
        int m = mt * 64 + 16 * w + 4 * (lane >> 4) + j;
        size_t idx = (((size_t)(b * 64 + c)) * 128 + m) * KH + n;
        Hr[idx] = f2bf(accr[mt][t][j] * inv);
        Hi[idx] = f2bf(acci[mt][t][j] * inv);
      }
    }
  }
}

// ------- K7: inverse W-DFT (fu = blockIdx.z), W-symmetric -------
__global__ __launch_bounds__(TPB) void k_dftw_inv_mfma(
    const us16* __restrict__ Hr0, const us16* __restrict__ Hi0,
    const us16* __restrict__ Hr1, const us16* __restrict__ Hi1,
    const us16* __restrict__ Tci, const us16* __restrict__ Tsi,
    float* __restrict__ out, int b0) {
  __shared__ __align__(16) us16 Ar[2][64][32];
  __shared__ __align__(16) us16 Ai[2][64][32];
  __shared__ __align__(16) us16 Bc[2][64][32];
  __shared__ __align__(16) us16 Bs[2][64][32];
  const int tid = threadIdx.x, w = tid >> 6, lane = tid & 63;
  const int w0 = blockIdx.x * 64, mf0 = blockIdx.y * 64;
  const int fu = blockIdx.z;
  const int roff = fu << 7;
  const us16* Hr = fu ? Hr1 : Hr0;
  const us16* Hi = fu ? Hi1 : Hi0;
  const int rsel = lane >> 2;
  const int csw = (lane & 3) ^ ((lane >> 3) & 3);
  const us16* gAr = Hr + (size_t)(mf0 + 16 * w + rsel) * KH + csw * 8;
  const us16* gAi = Hi + (size_t)(mf0 + 16 * w + rsel) * KH + csw * 8;
  const us16* gBc = Tci + (size_t)(w0 + 16 * w + rsel) * KH + csw * 8;
  const us16* gBs = Tsi + (size_t)(w0 + 16 * w + rsel) * KH + csw * 8;
  f32x4 accU[4] = {}, accV[4] = {};
  const int fr = lane & 15;
  const int kb = 8 * ((lane >> 4) ^ ((lane >> 1) & 3));
#define STAGE_K7(pp, k0) do { \
    gload16(gAr + (k0), &Ar[pp][16 * w][0]); \
    gload16(gAi + (k0), &Ai[pp][16 * w][0]); \
    gload16(gBc + (k0), &Bc[pp][16 * w][0]); \
    gload16(gBs + (k0), &Bs[pp][16 * w][0]); } while (0)
  STAGE_K7(0, 0);
  int pp = 0;
  for (int k0 = 0; k0 < KH; k0 += 32) {
    if (k0 + 32 < KH) { STAGE_K7(pp ^ 1, k0 + 32); WAITVM(4); }
    else WAITVM(0);
    BAR_ACQ();
    bf16x8 aR = *(const bf16x8*)&Ar[pp][16 * w + fr][kb];
    bf16x8 aI = *(const bf16x8*)&Ai[pp][16 * w + fr][kb];
    uint4 su = *(const uint4*)&aI;
    su.x ^= 0x80008000u; su.y ^= 0x80008000u; su.z ^= 0x80008000u; su.w ^= 0x80008000u;
    bf16x8 aIn = *(const bf16x8*)&su;
#pragma unroll
    for (int t = 0; t < 4; ++t) {
      bf16x8 bC = *(const bf16x8*)&Bc[pp][16 * t + fr][kb];
      bf16x8 bS = *(const bf16x8*)&Bs[pp][16 * t + fr][kb];
      accU[t] = MFMA(aR, bC, accU[t], 0, 0, 0);
      accV[t] = MFMA(aIn, bS, accV[t], 0, 0, 0);
    }
    BAR_REL();
    pp ^= 1;
  }
#pragma unroll
  for (int t = 0; t < 4; ++t) {
    int wv = w0 + 16 * t + fr;                 // 0..127
#pragma unroll
    for (int j = 0; j < 4; ++j) {
      int mf = mf0 + 16 * w + 4 * (lane >> 4) + j;
      int bcl = mf >> 7, mrow = mf & 127;
      int bb = b0 + (bcl >> 6), cc = bcl & 63;
      size_t obase = (((size_t)bb * CH + cc) * HIN + roff + mrow) * WIN;
      float U = accU[t][j], V = accV[t][j];
      out[obase + wv] = U + V;
      if (wv > 0) out[obase + 256 - wv] = U - V;
    }
  }
}

// ------- K8: missing column w=128 (fu = blockIdx.y) -------
__global__ __launch_bounds__(TPB) void k_w128(const us16* __restrict__ Hr0,
                                              const us16* __restrict__ Hr1,
                                              float* __restrict__ out, int b0) {
  const int mf = blockIdx.x * TPB + threadIdx.x;
  const int fu = blockIdx.y;
  const int roff = fu << 7;
  const us16* hr = (fu ? Hr1 : Hr0) + (size_t)mf * KH;
  float s = bf2f(hr[0]) + bf2f(hr[128]);
  for (int k = 1; k < 128; k += 2)
    s += -2.f * bf2f(hr[k]) + 2.f * bf2f(hr[k + 1]);
  s -= 2.f * bf2f(hr[128]);
  s *= (1.f / 256.f);
  int bcl = mf >> 7, mrow = mf & 127;
  int bb = b0 + (bcl >> 6), cc = bcl & 63;
  out[(((size_t)bb * CH + cc) * HIN + roff + mrow) * WIN + 128] = s;
}

// ---------------- host ----------------
extern "C" void kernel_launch(void* const* d_in, const int* in_sizes, int n_in,
                              void* d_out, int out_size, void* d_ws, size_t ws_size,
                              hipStream_t stream) {
  const float* x        = (const float*)d_in[0];
  const float* conv_w   = (const float*)d_in[1];
  const float* conv_b   = (const float*)d_in[2];
  const float* gn_gamma = (const float*)d_in[3];
  const float* gn_beta  = (const float*)d_in[4];
  float* out = (float*)d_out;

  // u16 units
  const size_t uCbA = 2 * 65536;
  const size_t uTcb = 128 * 256;
  const size_t uTci = (size_t)256 * KH;
  const size_t uW   = 128 * 128;
  const size_t fixed_u16 = 2 * uCbA + 2 * uTcb + 2 * uTci + 2 * uW;
  const size_t uXB = (size_t)CH * HIN * WIN;      // 4194304
  const size_t uF  = (size_t)CH * SP;             // 2113536
  const size_t uPQ = (size_t)128 * SP;            // 4227072
  const size_t uYT = (size_t)128 * SP;            // 4227072
  const size_t uH  = (size_t)CH * 128 * KH;       // 1310720
  const size_t uZ1 = (size_t)UZ * 128;            // 1056768 per Z array per fu per b
  // per-batch: xb + Frt/Fit + P/Q (reused as Z[2][4arrays]) + Yt1 + H1 pair
  const size_t per_u16 = uXB + 2 * uF + 2 * uPQ + uYT + 2 * uH;   // 23724032
  const size_t nPart = 2 * 4 * NBX * 4 + 256;     // part + stats floats

  int nb = 0;
  for (int cand = 4; cand >= 1; cand >>= 1) {
    size_t need = fixed_u16 * 2 + nPart * 4 + (size_t)cand * per_u16 * 2 + 256;
    if (need <= ws_size) { nb = cand; break; }
  }
  if (nb == 0) {
    k_zero<<<dim3((out_size + TPB - 1) / TPB), dim3(TPB), 0, stream>>>(out, out_size);
    return;
  }

  us16* CbA = (us16*)d_ws;
  us16* SbA = CbA + uCbA;
  us16* Tcb = SbA + uCbA;
  us16* Tsb = Tcb + uTcb;
  us16* Tci = Tsb + uTcb;
  us16* Tsi = Tci + uTci;
  us16* Wpb = Tsi + uTci;
  us16* Wqb = Wpb + uW;
  float* part  = (float*)(Wqb + uW);      // [fu][b][NBX][4]
  float* stats = part + 2 * 4 * NBX * 4;  // [fu][b*16][2]
  us16* xb  = (us16*)(stats + 256);
  us16* Frt = xb + (size_t)nb * uXB;
  us16* Fit = Frt + (size_t)nb * uF;
  us16* P   = Fit + (size_t)nb * uF;
  us16* Q   = P + (size_t)nb * uPQ;
  us16* Yt1 = Q + (size_t)nb * uPQ;
  us16* Hr1 = Yt1 + (size_t)nb * uYT;
  us16* Hi1 = Hr1 + (size_t)nb * uH;
  // Z arrays [fu][b] alias P/Q (dead after fwd2): 8*nb*uZ1 == 2*nb*uPQ exactly
  us16* Zrp = P;
  us16* Zrm = Zrp + 2 * (size_t)nb * uZ1;
  us16* Zip = Zrm + 2 * (size_t)nb * uZ1;
  us16* Zim = Zip + 2 * (size_t)nb * uZ1;
  // aliases into [xb | Frt | Fit] (dead after k_mix): Yt0 then H0 pair
  us16* Yt0 = xb;                               // uYT + 2*uH <= uXB + 2*uF
  us16* Hr0 = xb + (size_t)nb * uYT;
  us16* Hi0 = Hr0 + (size_t)nb * uH;

  k_tables<<<dim3(512), dim3(TPB), 0, stream>>>(CbA, SbA, Tcb, Tsb, Tci, Tsi,
                                                Wpb, Wqb, conv_w);

  for (int b0 = 0; b0 < B_ALL; b0 += nb) {
    k_xcast2<<<dim3(nb * 4096), dim3(TPB), 0, stream>>>(
        x + (size_t)b0 * CH * HIN * WIN, xb, Frt, Fit);
    k_dftw_fwd_mfma<<<dim3(nb * 256), dim3(TPB), 0, stream>>>(
        xb, Tcb, Tsb, Frt, Fit);
    k_mix<<<dim3(SP / 64, 1, nb), dim3(TPB), 0, stream>>>(
        Frt, Fit, Wpb, Wqb, P, Q);
    k_dfth_fwd2<<<dim3(NBX, 2, nb), dim3(TPB), 0, stream>>>(
        P, Q, CbA, SbA, conv_b, Yt0, Yt1, part);
    k_gn_stats2<<<dim3(nb * 16, 2), dim3(TPB), 0, stream>>>(part, stats);
    k_gnfold<<<dim3(UZ / 8, nb, 2), dim3(TPB), 0, stream>>>(
        Yt0, Yt1, stats, gn_gamma, gn_beta, Zrp, Zrm, Zip, Zim);
    k_dfth_inv_mfma<<<dim3(UZ / 64, 2, nb), dim3(TPB), 0, stream>>>(
        Zrp, Zrm, Zip, Zim, CbA, SbA, Hr0, Hi0, Hr1, Hi1);
    k_dftw_inv_mfma<<<dim3(2, nb * 128, 2), dim3(TPB), 0, stream>>>(
        Hr0, Hi0, Hr1, Hi1, Tci, Tsi, out, b0);
    k_w128<<<dim3(nb * 32, 2), dim3(TPB), 0, stream>>>(Hr0, Hr1, out, b0);
  }
}

// Round 22
// 223.210 us; speedup vs baseline: 1.1654x; 1.0052x over previous
//
#include <hip/hip_runtime.h>
#include <math.h>

#define TPB 256

typedef unsigned short us16;
typedef __bf16 bf16x8 __attribute__((ext_vector_type(8)));
typedef float f32x4 __attribute__((ext_vector_type(4)));

static const int B_ALL = 4;
static const int CH   = 64;
static const int HIN  = 256, WIN = 256;
static const int HH   = 255;
static const int WF   = 129;          // valid n per channel
static const int HWF  = HH * WF;      // 32895 valid GN count per channel
static const int SP   = WF * 256;     // 33024 packed spatial per channel
static const int KH   = 160;          // padded K for inverse W-DFT
static const int UZ   = 64 * WF;      // 8256 packed (c,n) rows per batch (inv side)
static const int NBX  = 258;          // fwd2 blocks per batch per fu
#define GN_EPS 1e-5f

__device__ __forceinline__ us16 f2bf(float f) {
  union { float f; unsigned u; } v; v.f = f;
  unsigned r = v.u + 0x7FFFu + ((v.u >> 16) & 1u);
  return (us16)(r >> 16);
}
__device__ __forceinline__ float bf2f(us16 v) {
  union { unsigned u; float f; } t; t.u = ((unsigned)v) << 16; return t.f;
}
__device__ __forceinline__ void gload16(const void* g, void* l) {
  __builtin_amdgcn_global_load_lds(
      (const __attribute__((address_space(1))) unsigned int*)g,
      (__attribute__((address_space(3))) unsigned int*)l, 16, 0, 0);
}
#define MFMA __builtin_amdgcn_mfma_f32_16x16x32_bf16
#define WAITVM(N) asm volatile("s_waitcnt vmcnt(" #N ")" ::: "memory")
#define WAITLGKM0 asm volatile("s_waitcnt lgkmcnt(0)" ::: "memory")
#define BAR_ACQ() do { \
    __builtin_amdgcn_s_barrier(); \
    asm volatile("" ::: "memory"); \
    __builtin_amdgcn_sched_barrier(0); } while (0)
#define BAR_REL() do { \
    asm volatile("" ::: "memory"); \
    __builtin_amdgcn_s_barrier(); } while (0)

// ---------------- fallback ----------------
__global__ __launch_bounds__(TPB) void k_zero(float* __restrict__ out, int n) {
  int i = blockIdx.x * TPB + threadIdx.x;
  if (i < n) out[i] = 0.f;
}

// ---------------- bf16 tables ----------------
__global__ __launch_bounds__(TPB) void k_tables(
    us16* __restrict__ CbA, us16* __restrict__ SbA,
    us16* __restrict__ Tcb, us16* __restrict__ Tsb,
    us16* __restrict__ Tci, us16* __restrict__ Tsi,
    us16* __restrict__ Wpb, us16* __restrict__ Wqb,
    const float* __restrict__ conv_w) {
  int i = blockIdx.x * TPB + threadIdx.x;
  const double PI2 = 6.283185307179586476925286766559;
  if (i < 2 * 65536) {                      // H-DFT [fu][r][k], k-shift absorbed
    int fu = i >> 16, r = (i >> 8) & 255, k = i & 255;
    float cv = 0.f, sv = 0.f;
    int kk = k - fu;
    if (r < 255 && kk >= 0 && kk < 255) {
      double ang = PI2 * (double)((r * kk) % 255) / 255.0;
      cv = (float)cos(ang); sv = (float)sin(ang);
    }
    CbA[i] = f2bf(cv); SbA[i] = f2bf(sv);
  }
  if (i < 128 * 256) {                      // W-DFT fwd transposed [n<128][w]
    int n = i >> 8, w = i & 255;
    double ang = PI2 * (double)((n * w) & 255) / 256.0;
    Tcb[i] = f2bf((float)cos(ang));
    Tsb[i] = f2bf((float)sin(ang));
  }
  if (i < 256 * KH) {                       // W-DFT inv [w][k], Hermitian coef
    int w = i / KH, k = i - w * KH;
    float cv = 0.f, sv = 0.f;
    if (k < WF) {
      double coef = (k == 0 || k == 128) ? 1.0 : 2.0;
      double ang = PI2 * (double)((k * w) & 255) / 256.0;
      cv = (float)(coef * cos(ang) / 256.0);
      sv = (float)(coef * sin(ang) / 256.0);
    }
    Tci[i] = f2bf(cv); Tsi[i] = f2bf(sv);
  }
  if (i < 128 * 128) {                      // mix weights
    int o = i >> 7, c = i & 127;
    Wpb[i] = f2bf(conv_w[i]);
    float q = (c < 64) ? -conv_w[o * 128 + 64 + c] : conv_w[o * 128 + c - 64];
    Wqb[i] = f2bf(q);
  }
}

// ------- K1: forward W-DFT, x read directly (cast fused), BOTH n-halves per block -------
__global__ __launch_bounds__(TPB) void k_dftw_fwd_mfma(
    const float* __restrict__ x, const us16* __restrict__ Tcb,
    const us16* __restrict__ Tsb, us16* __restrict__ Frt, us16* __restrict__ Fit) {
  __shared__ __align__(16) us16 Ac[2][2][64][32];   // [pp][half]
  __shared__ __align__(16) us16 As[2][2][64][32];
  __shared__ __align__(16) us16 Bx[2][64][32];
  __shared__ float nyqr[64][4];
  const int tid = threadIdx.x, w = tid >> 6, lane = tid & 63;
  const int hb = blockIdx.x;
  const int rsel = lane >> 2;
  const int csw = (lane & 3) ^ ((lane >> 3) & 3);
  const us16* gAc = Tcb + (size_t)(16 * w + rsel) * 256 + csw * 8;
  const us16* gAs = Tsb + (size_t)(16 * w + rsel) * 256 + csw * 8;
  const int srow = tid >> 2, ssub = tid & 3;        // staging: 4 threads/row, 8 w each
  const float* gx = x + ((size_t)hb * 64 + srow) * 256 + ssub * 8;
  float nyq = 0.f;
  f32x4 accr[2][4] = {}, acci[2][4] = {};
  const int fr = lane & 15;
  const int kb = 8 * ((lane >> 4) ^ ((lane >> 1) & 3));   // A frag (swizzled gload)
  const int kbB = 8 * (lane >> 4);                         // B frag (linear VALU-staged)
#define STAGE_K1(pp, k0) do { \
    float4 v0 = *(const float4*)(gx + (k0)); \
    float4 v1 = *(const float4*)(gx + (k0) + 4); \
    nyq += v0.x - v0.y + v0.z - v0.w + v1.x - v1.y + v1.z - v1.w; \
    uint4 pk; \
    pk.x = (unsigned)f2bf(v0.x) | ((unsigned)f2bf(v0.y) << 16); \
    pk.y = (unsigned)f2bf(v0.z) | ((unsigned)f2bf(v0.w) << 16); \
    pk.z = (unsigned)f2bf(v1.x) | ((unsigned)f2bf(v1.y) << 16); \
    pk.w = (unsigned)f2bf(v1.z) | ((unsigned)f2bf(v1.w) << 16); \
    *(uint4*)&Bx[pp][srow][ssub * 8] = pk; \
    gload16(gAc + (k0), &Ac[pp][0][16 * w][0]); \
    gload16(gAc + 64 * 256 + (k0), &Ac[pp][1][16 * w][0]); \
    gload16(gAs + (k0), &As[pp][0][16 * w][0]); \
    gload16(gAs + 64 * 256 + (k0), &As[pp][1][16 * w][0]); } while (0)
  STAGE_K1(0, 0);
  int pp = 0;
  for (int k0 = 0; k0 < 256; k0 += 32) {
    if (k0 + 32 < 256) { STAGE_K1(pp ^ 1, k0 + 32); WAITVM(4); }
    else WAITVM(0);
    WAITLGKM0;
    BAR_ACQ();
    bf16x8 aC[2], aSn[2];
#pragma unroll
    for (int g = 0; g < 2; ++g) {
      aC[g] = *(const bf16x8*)&Ac[pp][g][16 * w + fr][kb];
      bf16x8 aS = *(const bf16x8*)&As[pp][g][16 * w + fr][kb];
      uint4 su = *(const uint4*)&aS;
      su.x ^= 0x80008000u; su.y ^= 0x80008000u; su.z ^= 0x80008000u; su.w ^= 0x80008000u;
      aSn[g] = *(const bf16x8*)&su;
    }
#pragma unroll
    for (int t = 0; t < 4; ++t) {
      bf16x8 b = *(const bf16x8*)&Bx[pp][16 * t + fr][kbB];
#pragma unroll
      for (int g = 0; g < 2; ++g) {
        accr[g][t] = MFMA(aC[g], b, accr[g][t], 0, 0, 0);
        acci[g][t] = MFMA(aSn[g], b, acci[g][t], 0, 0, 0);
      }
    }
    BAR_REL();
    pp ^= 1;
  }
  const int bc = hb >> 2, hl = (hb & 3) * 64;
#pragma unroll
  for (int g = 0; g < 2; ++g) {
#pragma unroll
    for (int t = 0; t < 4; ++t) {
      int h = hl + 16 * t + fr;
#pragma unroll
      for (int j = 0; j < 4; ++j) {
        int n = g * 64 + 16 * w + 4 * (lane >> 4) + j;
        size_t idx = ((size_t)bc * WF + n) * 256 + h;
        Frt[idx] = f2bf(accr[g][t][j]);
        Fit[idx] = f2bf(acci[g][t][j]);
      }
    }
  }
  nyqr[srow][ssub] = nyq;
  __syncthreads();
  if (ssub == 0) {
    float a = nyqr[srow][0] + nyqr[srow][1] + nyqr[srow][2] + nyqr[srow][3];
    int h = hl + srow - hl + ((hb & 3) * 64 + srow) - ((hb & 3) * 64 + srow) + ((hb & 3) * 64 + srow); // = (hb&3)*64 + srow
    size_t idx = ((size_t)bc * WF + 128) * 256 + h;
    Frt[idx] = f2bf(a);
    Fit[idx] = 0;
  }
}

// ------- K2: channel-mix, BOTH o-tiles per block (B staged once) -------
__global__ __launch_bounds__(TPB) void k_mix(
    const us16* __restrict__ Frt, const us16* __restrict__ Fit,
    const us16* __restrict__ Wpb, const us16* __restrict__ Wqb,
    us16* __restrict__ P, us16* __restrict__ Q) {
  __shared__ __align__(16) us16 Ap[2][64][32];
  __shared__ __align__(16) us16 Aq[2][64][32];
  __shared__ __align__(8)  us16 Bs[64][36];
  const int tid = threadIdx.x, w = tid >> 6, lane = tid & 63;
  const int sp0 = blockIdx.x * 64, b = blockIdx.z;
  const int rsel = lane >> 2;
  const int csw = (lane & 3) ^ ((lane >> 3) & 3);
  const us16* gAp0 = Wpb + (size_t)(16 * w + rsel) * 128 + csw * 8;
  const us16* gAq0 = Wqb + (size_t)(16 * w + rsel) * 128 + csw * 8;
  f32x4 accp[2][4] = {}, accq[2][4] = {};
  const int fr = lane & 15;
  const int kbA = 8 * ((lane >> 4) ^ ((lane >> 1) & 3));
  const int kbB = 8 * (lane >> 4);
  for (int c0 = 0; c0 < 128; c0 += 32) {
    gload16(gAp0 + c0, &Ap[0][16 * w][0]);
    gload16(gAp0 + 64 * 128 + c0, &Ap[1][16 * w][0]);
    gload16(gAq0 + c0, &Aq[0][16 * w][0]);
    gload16(gAq0 + 64 * 128 + c0, &Aq[1][16 * w][0]);
    for (int f = tid; f < 1024; f += TPB) {
      int cl = f >> 5, spp = f & 31;
      int c = c0 + cl;
      const us16* src = (c < 64) ? Frt : Fit;
      size_t addr = (size_t)(b * 64 + (c & 63)) * SP + sp0 + 2 * spp;
      unsigned v = *(const unsigned*)(src + addr);
      Bs[2 * spp][cl] = (us16)v;
      Bs[2 * spp + 1][cl] = (us16)(v >> 16);
    }
    __syncthreads();
    bf16x8 aP0 = *(const bf16x8*)&Ap[0][16 * w + fr][kbA];
    bf16x8 aP1 = *(const bf16x8*)&Ap[1][16 * w + fr][kbA];
    bf16x8 aQ0 = *(const bf16x8*)&Aq[0][16 * w + fr][kbA];
    bf16x8 aQ1 = *(const bf16x8*)&Aq[1][16 * w + fr][kbA];
#pragma unroll
    for (int t = 0; t < 4; ++t) {
      uint2 lo = *(const uint2*)&Bs[16 * t + fr][kbB];
      uint2 hi = *(const uint2*)&Bs[16 * t + fr][kbB + 4];
      uint4 qq; qq.x = lo.x; qq.y = lo.y; qq.z = hi.x; qq.w = hi.y;
      bf16x8 bb = *(const bf16x8*)&qq;
      accp[0][t] = MFMA(aP0, bb, accp[0][t], 0, 0, 0);
      accp[1][t] = MFMA(aP1, bb, accp[1][t], 0, 0, 0);
      accq[0][t] = MFMA(aQ0, bb, accq[0][t], 0, 0, 0);
      accq[1][t] = MFMA(aQ1, bb, accq[1][t], 0, 0, 0);
    }
    __syncthreads();
  }
#pragma unroll
  for (int t = 0; t < 4; ++t) {
    int sp = sp0 + 16 * t + fr;
#pragma unroll
    for (int ot = 0; ot < 2; ++ot)
#pragma unroll
      for (int j = 0; j < 4; ++j) {
        int o = ot * 64 + 16 * w + 4 * (lane >> 4) + j;
        size_t idx = (size_t)(b * 128 + o) * SP + sp;
        P[idx] = f2bf(accp[ot][t][j]);
        Q[idx] = f2bf(accq[ot][t][j]);
      }
  }
}

// ------- K3: H-DFT fwd, fu = blockIdx.y; M-symmetric + fused GN partial stats -------
__global__ __launch_bounds__(TPB) void k_dfth_fwd2(
    const us16* __restrict__ P, const us16* __restrict__ Q,
    const us16* __restrict__ CbA, const us16* __restrict__ SbA,
    const float* __restrict__ bias, us16* __restrict__ Yt0,
    us16* __restrict__ Yt1, float* __restrict__ gnpart) {
  __shared__ __align__(16) us16 Ac[2][2][64][32];
  __shared__ __align__(16) us16 As[2][2][64][32];
  __shared__ __align__(16) us16 Bp[2][64][32];
  __shared__ __align__(16) us16 Bq[2][64][32];
  __shared__ float red[4 * TPB];
  const int tid = threadIdx.x, w = tid >> 6, lane = tid & 63;
  const int fu = blockIdx.y;
  const int b = blockIdx.z;
  const int u0 = blockIdx.x * 64;
  const int rsel = lane >> 2;
  const int csw = (lane & 3) ^ ((lane >> 3) & 3);
  const us16* gAc = CbA + (((size_t)fu * 256 + 16 * w + rsel) << 8) + csw * 8;
  const us16* gAs = SbA + (((size_t)fu * 256 + 16 * w + rsel) << 8) + csw * 8;
  const us16* gBp = P + (size_t)b * 128 * SP + (size_t)(u0 + 16 * w + rsel) * 256 + csw * 8;
  const us16* gBq = Q + (size_t)b * 128 * SP + (size_t)(u0 + 16 * w + rsel) * 256 + csw * 8;
  f32x4 cp[2][4] = {}, sq[2][4] = {};
  const int fr = lane & 15;
  const int kb = 8 * ((lane >> 4) ^ ((lane >> 1) & 3));
#define STAGE_K3(pp, k0) do { \
    _Pragma("unroll") \
    for (int mt = 0; mt < 2; ++mt) { \
      gload16(gAc + (mt << 14) + (k0), &Ac[pp][mt][16 * w][0]); \
      gload16(gAs + (mt << 14) + (k0), &As[pp][mt][16 * w][0]); } \
    gload16(gBp + (k0), &Bp[pp][16 * w][0]); \
    gload16(gBq + (k0), &Bq[pp][16 * w][0]); } while (0)
  STAGE_K3(0, 0);
  int pp = 0;
  for (int k0 = 0; k0 < 256; k0 += 32) {
    if (k0 + 32 < 256) { STAGE_K3(pp ^ 1, k0 + 32); WAITVM(6); }
    else WAITVM(0);
    BAR_ACQ();
    bf16x8 aC[2], aS[2];
#pragma unroll
    for (int mt = 0; mt < 2; ++mt) {
      aC[mt] = *(const bf16x8*)&Ac[pp][mt][16 * w + fr][kb];
      aS[mt] = *(const bf16x8*)&As[pp][mt][16 * w + fr][kb];
    }
#pragma unroll
    for (int t = 0; t < 4; ++t) {
      bf16x8 bP = *(const bf16x8*)&Bp[pp][16 * t + fr][kb];
      bf16x8 bQ = *(const bf16x8*)&Bq[pp][16 * t + fr][kb];
#pragma unroll
      for (int mt = 0; mt < 2; ++mt) {
        cp[mt][t] = MFMA(aC[mt], bP, cp[mt][t], 0, 0, 0);
        sq[mt][t] = MFMA(aS[mt], bQ, sq[mt][t], 0, 0, 0);
      }
    }
    BAR_REL();
    pp ^= 1;
  }
  us16* yb = (fu ? Yt1 : Yt0) + (size_t)b * 128 * SP;
  const int mb_ = 16 * w + 4 * (lane >> 4);
  const int ub = (u0 / WF + 1) * WF;           // first u of bucket-1 channel
  float s0 = 0.f, q0 = 0.f, s1 = 0.f, q1 = 0.f;
#pragma unroll
  for (int t = 0; t < 4; ++t) {
    int u = u0 + 16 * t + fr;
    float bo = bias[u / WF];
    float ts = 0.f, tq = 0.f;
#pragma unroll
    for (int mt = 0; mt < 2; ++mt) {
      int base = mt * 64 + mb_;                // r = base + j, 0..127
      float y[4], z[4];
#pragma unroll
      for (int j = 0; j < 4; ++j) {
        y[j] = cp[mt][t][j] + sq[mt][t][j] + bo; // row r
        z[j] = cp[mt][t][j] - sq[mt][t][j] + bo; // row 255-r
        ts += y[j]; tq += y[j] * y[j];
        if (base + j) { ts += z[j]; tq += z[j] * z[j]; }  // skip m==255 pad
      }
      uint2 pk;
      pk.x = (unsigned)f2bf(y[0]) | ((unsigned)f2bf(y[1]) << 16);
      pk.y = (unsigned)f2bf(y[2]) | ((unsigned)f2bf(y[3]) << 16);
      *(uint2*)(yb + (size_t)u * 256 + base) = pk;
      uint2 pk2;                               // reversed: m' = 252-base .. 255-base
      pk2.x = (unsigned)f2bf(z[3]) | ((unsigned)f2bf(z[2]) << 16);
      pk2.y = (unsigned)f2bf(z[1]) | ((unsigned)f2bf(z[0]) << 16);
      *(uint2*)(yb + (size_t)u * 256 + 252 - base) = pk2;
    }
    if (u >= ub) { s1 += ts; q1 += tq; } else { s0 += ts; q0 += tq; }
  }
  __syncthreads();
  red[tid] = s0; red[TPB + tid] = q0;
  red[2 * TPB + tid] = s1; red[3 * TPB + tid] = q1;
  __syncthreads();
  for (int st = TPB / 2; st > 0; st >>= 1) {
    if (tid < st) {
      red[tid] += red[tid + st];
      red[TPB + tid] += red[TPB + tid + st];
      red[2 * TPB + tid] += red[2 * TPB + tid + st];
      red[3 * TPB + tid] += red[3 * TPB + tid + st];
    }
    __syncthreads();
  }
  if (tid == 0) {
    float* gp = gnpart + ((((size_t)fu * gridDim.z) + b) * NBX + blockIdx.x) * 4;
    gp[0] = red[0]; gp[1] = red[TPB];
    gp[2] = red[2 * TPB]; gp[3] = red[3 * TPB];
  }
}

// ---- K4: reduce fwd2 partials -> per-group stats (fu = blockIdx.y) ----
__global__ __launch_bounds__(TPB) void k_gn_stats2(const float* __restrict__ part,
                                                   float* __restrict__ stats) {
  const int bg = blockIdx.x, b = bg >> 4, g = bg & 15;
  const int fu = blockIdx.y;
  const int nbv = gridDim.x >> 4;
  const float* pbase = part + (size_t)fu * nbv * NBX * 4;
  const int tid = threadIdx.x;
  const int clo = g * 8, chi = clo + 8;
  float s = 0.f, ss = 0.f;
  for (int bx = tid; bx < NBX; bx += TPB) {
    int c0 = (bx * 64) / WF;
    int c1 = (bx * 64 + 63) / WF;
    const float* p = pbase + ((size_t)b * NBX + bx) * 4;
    if (c0 >= clo && c0 < chi) { s += p[0]; ss += p[1]; }
    if (c1 != c0 && c1 >= clo && c1 < chi) { s += p[2]; ss += p[3]; }
  }
  __shared__ float rs[TPB], rq[TPB];
  rs[tid] = s; rq[tid] = ss;
  __syncthreads();
  for (int st = TPB / 2; st > 0; st >>= 1) {
    if (tid < st) { rs[tid] += rs[tid + st]; rq[tid] += rq[tid + st]; }
    __syncthreads();
  }
  if (tid == 0) {
    const float inv = 1.f / (8.f * (float)HWF);
    float mean = rs[0] * inv;
    float var = rq[0] * inv - mean * mean;
    float* sb = stats + (size_t)fu * nbv * 32;
    sb[bg * 2] = mean;
    sb[bg * 2 + 1] = rsqrtf(var + GN_EPS);
  }
}

// ------- K5: GN+ReLU + k-fold (fu = blockIdx.z): Z+/- [fu][b][u'][k] -------
__global__ __launch_bounds__(TPB) void k_gnfold(
    const us16* __restrict__ Yt0, const us16* __restrict__ Yt1,
    const float* __restrict__ stats,
    const float* __restrict__ gamma, const float* __restrict__ beta,
    us16* __restrict__ Zrp, us16* __restrict__ Zrm,
    us16* __restrict__ Zip, us16* __restrict__ Zim) {
  const int b = blockIdx.y;
  const int fu = blockIdx.z;
  const int nbv = gridDim.y;
  const int up = blockIdx.x * 8 + (threadIdx.x >> 5);   // 0..8255
  const int l32 = threadIdx.x & 31;
  const int c = up / WF;
  const float* sb = stats + (size_t)fu * nbv * 32;
  const int g1 = b * 16 + (c >> 3), g2 = g1 + 8;
  const float sc1 = gamma[c] * sb[g1 * 2 + 1];
  const float sh1 = beta[c] - sb[g1 * 2] * sc1;
  const float sc2 = gamma[64 + c] * sb[g2 * 2 + 1];
  const float sh2 = beta[64 + c] - sb[g2 * 2] * sc2;
  const us16* ybase = (fu ? Yt1 : Yt0) + (size_t)b * 128 * SP;
  const us16* yr = ybase + (size_t)up * 256;
  const us16* yi = ybase + (size_t)(64 * WF + up) * 256;
  const int k0 = l32 * 4;
  uint2 ar = *(const uint2*)(yr + k0);
  uint2 mr = *(const uint2*)(yr + 252 - k0);
  uint2 ai = *(const uint2*)(yi + k0);
  uint2 mi = *(const uint2*)(yi + 252 - k0);
  us16 arv[4] = {(us16)ar.x, (us16)(ar.x >> 16), (us16)ar.y, (us16)(ar.y >> 16)};
  us16 mrv[4] = {(us16)mr.x, (us16)(mr.x >> 16), (us16)mr.y, (us16)(mr.y >> 16)};
  us16 aiv[4] = {(us16)ai.x, (us16)(ai.x >> 16), (us16)ai.y, (us16)(ai.y >> 16)};
  us16 miv[4] = {(us16)mi.x, (us16)(mi.x >> 16), (us16)mi.y, (us16)(mi.y >> 16)};
  us16 rp[4], rm[4], ip[4], im[4];
#pragma unroll
  for (int d = 0; d < 4; ++d) {
    float zr = fmaxf(bf2f(arv[d]) * sc1 + sh1, 0.f);
    float zi = fmaxf(bf2f(aiv[d]) * sc2 + sh2, 0.f);
    float pr = 0.f, pi = 0.f;
    if (k0 + d > 0) {
      pr = fmaxf(bf2f(mrv[3 - d]) * sc1 + sh1, 0.f);
      pi = fmaxf(bf2f(miv[3 - d]) * sc2 + sh2, 0.f);
    }
    rp[d] = f2bf(zr + pr); rm[d] = f2bf(zr - pr);
    ip[d] = f2bf(zi + pi); im[d] = f2bf(zi - pi);
  }
  const size_t zo = (((size_t)fu * nbv + b) * UZ + up) * 128 + k0;
  uint2 o1; o1.x = (unsigned)rp[0] | ((unsigned)rp[1] << 16);
  o1.y = (unsigned)rp[2] | ((unsigned)rp[3] << 16);
  *(uint2*)(Zrp + zo) = o1;
  uint2 o2; o2.x = (unsigned)rm[0] | ((unsigned)rm[1] << 16);
  o2.y = (unsigned)rm[2] | ((unsigned)rm[3] << 16);
  *(uint2*)(Zrm + zo) = o2;
  uint2 o3; o3.x = (unsigned)ip[0] | ((unsigned)ip[1] << 16);
  o3.y = (unsigned)ip[2] | ((unsigned)ip[3] << 16);
  *(uint2*)(Zip + zo) = o3;
  uint2 o4; o4.x = (unsigned)im[0] | ((unsigned)im[1] << 16);
  o4.y = (unsigned)im[2] | ((unsigned)im[3] << 16);
  *(uint2*)(Zim + zo) = o4;
}

// ------- K6: inverse H-DFT (fu = blockIdx.y), K folded to 128 -> H[fu] -------
__global__ __launch_bounds__(TPB) void k_dfth_inv_mfma(
    const us16* __restrict__ Zrp, const us16* __restrict__ Zrm,
    const us16* __restrict__ Zip, const us16* __restrict__ Zim,
    const us16* __restrict__ CbA, const us16* __restrict__ SbA,
    us16* __restrict__ Hr0, us16* __restrict__ Hi0,
    us16* __restrict__ Hr1, us16* __restrict__ Hi1) {
  __shared__ __align__(16) us16 Ac[2][2][64][32];
  __shared__ __align__(16) us16 As[2][2][64][32];
  __shared__ __align__(16) us16 Brp[2][64][32];
  __shared__ __align__(16) us16 Brm[2][64][32];
  __shared__ __align__(16) us16 Bip[2][64][32];
  __shared__ __align__(16) us16 Bim[2][64][32];
  const int tid = threadIdx.x, w = tid >> 6, lane = tid & 63;
  const int fu = blockIdx.y;
  const int b = blockIdx.z;
  const int nbv = gridDim.z;
  const int hsel = fu ? 127 : 0;
  const int u0 = blockIdx.x * 64;
  const int rsel = lane >> 2;
  const int csw = (lane & 3) ^ ((lane >> 3) & 3);
  const us16* gAc = CbA + (((size_t)hsel + 16 * w + rsel) << 8) + csw * 8;
  const us16* gAs = SbA + (((size_t)hsel + 16 * w + rsel) << 8) + csw * 8;
  const size_t zoff = (((size_t)fu * nbv + b) * UZ + u0 + 16 * w + rsel) * 128 + csw * 8;
  const us16* gZrp = Zrp + zoff;
  const us16* gZrm = Zrm + zoff;
  const us16* gZip = Zip + zoff;
  const us16* gZim = Zim + zoff;
  f32x4 accr[2][4] = {}, acci[2][4] = {};
  const int fr = lane & 15;
  const int kb = 8 * ((lane >> 4) ^ ((lane >> 1) & 3));
#define STAGE_K6(pp, k0) do { \
    gload16(gAc + (k0), &Ac[pp][0][16 * w][0]); \
    gload16(gAc + (1 << 14) + (k0), &Ac[pp][1][16 * w][0]); \
    gload16(gAs + (k0), &As[pp][0][16 * w][0]); \
    gload16(gAs + (1 << 14) + (k0), &As[pp][1][16 * w][0]); \
    gload16(gZrp + (k0), &Brp[pp][16 * w][0]); \
    gload16(gZrm + (k0), &Brm[pp][16 * w][0]); \
    gload16(gZip + (k0), &Bip[pp][16 * w][0]); \
    gload16(gZim + (k0), &Bim[pp][16 * w][0]); } while (0)
  STAGE_K6(0, 0);
  int pp = 0;
  for (int k0 = 0; k0 < 128; k0 += 32) {
    if (k0 + 32 < 128) { STAGE_K6(pp ^ 1, k0 + 32); WAITVM(8); }
    else WAITVM(0);
    BAR_ACQ();
    bf16x8 aC[2], aS[2], aSn[2];
#pragma unroll
    for (int mt = 0; mt < 2; ++mt) {
      aC[mt] = *(const bf16x8*)&Ac[pp][mt][16 * w + fr][kb];
      aS[mt] = *(const bf16x8*)&As[pp][mt][16 * w + fr][kb];
      uint4 su = *(const uint4*)&aS[mt];
      su.x ^= 0x80008000u; su.y ^= 0x80008000u; su.z ^= 0x80008000u; su.w ^= 0x80008000u;
      aSn[mt] = *(const bf16x8*)&su;
    }
#pragma unroll
    for (int t = 0; t < 4; ++t) {
      bf16x8 bRp = *(const bf16x8*)&Brp[pp][16 * t + fr][kb];
      bf16x8 bRm = *(const bf16x8*)&Brm[pp][16 * t + fr][kb];
      bf16x8 bIp = *(const bf16x8*)&Bip[pp][16 * t + fr][kb];
      bf16x8 bIm = *(const bf16x8*)&Bim[pp][16 * t + fr][kb];
#pragma unroll
      for (int mt = 0; mt < 2; ++mt) {
        accr[mt][t] = MFMA(aC[mt], bRp, accr[mt][t], 0, 0, 0);
        accr[mt][t] = MFMA(aSn[mt], bIm, accr[mt][t], 0, 0, 0);
        acci[mt][t] = MFMA(aC[mt], bIp, acci[mt][t], 0, 0, 0);
        acci[mt][t] = MFMA(aS[mt], bRm, acci[mt][t], 0, 0, 0);
      }
    }
    BAR_REL();
    pp ^= 1;
  }
  us16* Hr = fu ? Hr1 : Hr0;
  us16* Hi = fu ? Hi1 : Hi0;
  const float inv = 1.f / 255.f;
#pragma unroll
  for (int t = 0; t < 4; ++t) {
    int u = u0 + 16 * t + fr;
    int c = u / WF, n = u - c * WF;
#pragma unroll
    for (int mt = 0; mt < 2; ++mt) {
#pragma unroll
      for (int j = 0; j < 4; ++j) {
        int m = mt * 64 + 16 * w + 4 * (lane >> 4) + j;
        size_t idx = (((size_t)(b * 64 + c)) * 128 + m) * KH + n;
        Hr[idx] = f2bf(accr[mt][t][j] * inv);
        Hi[idx] = f2bf(acci[mt][t][j] * inv);
      }
    }
  }
}

// ------- K7: inverse W-DFT (fu = blockIdx.z), W-symmetric -------
__global__ __launch_bounds__(TPB) void k_dftw_inv_mfma(
    const us16* __restrict__ Hr0, const us16* __restrict__ Hi0,
    const us16* __restrict__ Hr1, const us16* __restrict__ Hi1,
    const us16* __restrict__ Tci, const us16* __restrict__ Tsi,
    float* __restrict__ out, int b0) {
  __shared__ __align__(16) us16 Ar[2][64][32];
  __shared__ __align__(16) us16 Ai[2][64][32];
  __shared__ __align__(16) us16 Bc[2][64][32];
  __shared__ __align__(16) us16 Bs[2][64][32];
  const int tid = threadIdx.x, w = tid >> 6, lane = tid & 63;
  const int w0 = blockIdx.x * 64, mf0 = blockIdx.y * 64;
  const int fu = blockIdx.z;
  const int roff = fu << 7;
  const us16* Hr = fu ? Hr1 : Hr0;
  const us16* Hi = fu ? Hi1 : Hi0;
  const int rsel = lane >> 2;
  const int csw = (lane & 3) ^ ((lane >> 3) & 3);
  const us16* gAr = Hr + (size_t)(mf0 + 16 * w + rsel) * KH + csw * 8;
  const us16* gAi = Hi + (size_t)(mf0 + 16 * w + rsel) * KH + csw * 8;
  const us16* gBc = Tci + (size_t)(w0 + 16 * w + rsel) * KH + csw * 8;
  const us16* gBs = Tsi + (size_t)(w0 + 16 * w + rsel) * KH + csw * 8;
  f32x4 accU[4] = {}, accV[4] = {};
  const int fr = lane & 15;
  const int kb = 8 * ((lane >> 4) ^ ((lane >> 1) & 3));
#define STAGE_K7(pp, k0) do { \
    gload16(gAr + (k0), &Ar[pp][16 * w][0]); \
    gload16(gAi + (k0), &Ai[pp][16 * w][0]); \
    gload16(gBc + (k0), &Bc[pp][16 * w][0]); \
    gload16(gBs + (k0), &Bs[pp][16 * w][0]); } while (0)
  STAGE_K7(0, 0);
  int pp = 0;
  for (int k0 = 0; k0 < KH; k0 += 32) {
    if (k0 + 32 < KH) { STAGE_K7(pp ^ 1, k0 + 32); WAITVM(4); }
    else WAITVM(0);
    BAR_ACQ();
    bf16x8 aR = *(const bf16x8*)&Ar[pp][16 * w + fr][kb];
    bf16x8 aI = *(const bf16x8*)&Ai[pp][16 * w + fr][kb];
    uint4 su = *(const uint4*)&aI;
    su.x ^= 0x80008000u; su.y ^= 0x80008000u; su.z ^= 0x80008000u; su.w ^= 0x80008000u;
    bf16x8 aIn = *(const bf16x8*)&su;
#pragma unroll
    for (int t = 0; t < 4; ++t) {
      bf16x8 bC = *(const bf16x8*)&Bc[pp][16 * t + fr][kb];
      bf16x8 bS = *(const bf16x8*)&Bs[pp][16 * t + fr][kb];
      accU[t] = MFMA(aR, bC, accU[t], 0, 0, 0);
      accV[t] = MFMA(aIn, bS, accV[t], 0, 0, 0);
    }
    BAR_REL();
    pp ^= 1;
  }
#pragma unroll
  for (int t = 0; t < 4; ++t) {
    int wv = w0 + 16 * t + fr;                 // 0..127
#pragma unroll
    for (int j = 0; j < 4; ++j) {
      int mf = mf0 + 16 * w + 4 * (lane >> 4) + j;
      int bcl = mf >> 7, mrow = mf & 127;
      int bb = b0 + (bcl >> 6), cc = bcl & 63;
      size_t obase = (((size_t)bb * CH + cc) * HIN + roff + mrow) * WIN;
      float U = accU[t][j], V = accV[t][j];
      out[obase + wv] = U + V;
      if (wv > 0) out[obase + 256 - wv] = U - V;
    }
  }
}

// ------- K8: missing column w=128 (fu = blockIdx.y) -------
__global__ __launch_bounds__(TPB) void k_w128(const us16* __restrict__ Hr0,
                                              const us16* __restrict__ Hr1,
                                              float* __restrict__ out, int b0) {
  const int mf = blockIdx.x * TPB + threadIdx.x;
  const int fu = blockIdx.y;
  const int roff = fu << 7;
  const us16* hr = (fu ? Hr1 : Hr0) + (size_t)mf * KH;
  float s = bf2f(hr[0]) + bf2f(hr[128]);
  for (int k = 1; k < 128; k += 2)
    s += -2.f * bf2f(hr[k]) + 2.f * bf2f(hr[k + 1]);
  s -= 2.f * bf2f(hr[128]);
  s *= (1.f / 256.f);
  int bcl = mf >> 7, mrow = mf & 127;
  int bb = b0 + (bcl >> 6), cc = bcl & 63;
  out[(((size_t)bb * CH + cc) * HIN + roff + mrow) * WIN + 128] = s;
}

// ---------------- host ----------------
extern "C" void kernel_launch(void* const* d_in, const int* in_sizes, int n_in,
                              void* d_out, int out_size, void* d_ws, size_t ws_size,
                              hipStream_t stream) {
  const float* x        = (const float*)d_in[0];
  const float* conv_w   = (const float*)d_in[1];
  const float* conv_b   = (const float*)d_in[2];
  const float* gn_gamma = (const float*)d_in[3];
  const float* gn_beta  = (const float*)d_in[4];
  float* out = (float*)d_out;

  // u16 units
  const size_t uCbA = 2 * 65536;
  const size_t uTcb = 128 * 256;
  const size_t uTci = (size_t)256 * KH;
  const size_t uW   = 128 * 128;
  const size_t fixed_u16 = 2 * uCbA + 2 * uTcb + 2 * uTci + 2 * uW;
  const size_t uXB = (size_t)CH * HIN * WIN;      // scratch region (alias target)
  const size_t uF  = (size_t)CH * SP;             // 2113536
  const size_t uPQ = (size_t)128 * SP;            // 4227072
  const size_t uYT = (size_t)128 * SP;            // 4227072
  const size_t uH  = (size_t)CH * 128 * KH;       // 1310720
  const size_t uZ1 = (size_t)UZ * 128;            // 1056768
  const size_t per_u16 = uXB + 2 * uF + 2 * uPQ + uYT + 2 * uH;   // 23724032
  const size_t nPart = 2 * 4 * NBX * 4 + 256;

  int nb = 0;
  for (int cand = 4; cand >= 1; cand >>= 1) {
    size_t need = fixed_u16 * 2 + nPart * 4 + (size_t)cand * per_u16 * 2 + 256;
    if (need <= ws_size) { nb = cand; break; }
  }
  if (nb == 0) {
    k_zero<<<dim3((out_size + TPB - 1) / TPB), dim3(TPB), 0, stream>>>(out, out_size);
    return;
  }

  us16* CbA = (us16*)d_ws;
  us16* SbA = CbA + uCbA;
  us16* Tcb = SbA + uCbA;
  us16* Tsb = Tcb + uTcb;
  us16* Tci = Tsb + uTcb;
  us16* Tsi = Tci + uTci;
  us16* Wpb = Tsi + uTci;
  us16* Wqb = Wpb + uW;
  float* part  = (float*)(Wqb + uW);      // [fu][b][NBX][4]
  float* stats = part + 2 * 4 * NBX * 4;  // [fu][b*16][2]
  us16* scratch = (us16*)(stats + 256);
  us16* Frt = scratch + (size_t)nb * uXB;
  us16* Fit = Frt + (size_t)nb * uF;
  us16* P   = Fit + (size_t)nb * uF;
  us16* Q   = P + (size_t)nb * uPQ;
  us16* Yt1 = Q + (size_t)nb * uPQ;
  us16* Hr1 = Yt1 + (size_t)nb * uYT;
  us16* Hi1 = Hr1 + (size_t)nb * uH;
  us16* Zrp = P;                                // alias P/Q (dead after fwd2)
  us16* Zrm = Zrp + 2 * (size_t)nb * uZ1;
  us16* Zip = Zrm + 2 * (size_t)nb * uZ1;
  us16* Zim = Zip + 2 * (size_t)nb * uZ1;
  us16* Yt0 = scratch;                          // uYT + 2*uH <= uXB + 2*uF
  us16* Hr0 = scratch + (size_t)nb * uYT;
  us16* Hi0 = Hr0 + (size_t)nb * uH;

  k_tables<<<dim3(512), dim3(TPB), 0, stream>>>(CbA, SbA, Tcb, Tsb, Tci, Tsi,
                                                Wpb, Wqb, conv_w);

  for (int b0 = 0; b0 < B_ALL; b0 += nb) {
    k_dftw_fwd_mfma<<<dim3(nb * 256), dim3(TPB), 0, stream>>>(
        x + (size_t)b0 * CH * HIN * WIN, Tcb, Tsb, Frt, Fit);
    k_mix<<<dim3(SP / 64, 1, nb), dim3(TPB), 0, stream>>>(
        Frt, Fit, Wpb, Wqb, P, Q);
    k_dfth_fwd2<<<dim3(NBX, 2, nb), dim3(TPB), 0, stream>>>(
        P, Q, CbA, SbA, conv_b, Yt0, Yt1, part);
    k_gn_stats2<<<dim3(nb * 16, 2), dim3(TPB), 0, stream>>>(part, stats);
    k_gnfold<<<dim3(UZ / 8, nb, 2), dim3(TPB), 0, stream>>>(
        Yt0, Yt1, stats, gn_gamma, gn_beta, Zrp, Zrm, Zip, Zim);
    k_dfth_inv_mfma<<<dim3(UZ / 64, 2, nb), dim3(TPB), 0, stream>>>(
        Zrp, Zrm, Zip, Zim, CbA, SbA, Hr0, Hi0, Hr1, Hi1);
    k_dftw_inv_mfma<<<dim3(2, nb * 128, 2), dim3(TPB), 0, stream>>>(
        Hr0, Hi0, Hr1, Hi1, Tci, Tsi, out, b0);
    k_w128<<<dim3(nb * 32, 2), dim3(TPB), 0, stream>>>(Hr0, Hr1, out, b0);
  }
}